// Round 6
// baseline (323.210 us; speedup 1.0000x reference)
//
#include <hip/hip_runtime.h>
#include <cstddef>
#include <cstdint>

// ---------------------------------------------------------------------------
// PatchAttention, algebraically simplified + bf16 MFMA GEMMs.
// 7 dispatches: prep_all (+xbar partials, +weight transposes) -> qdot+ubar
//               (+softmax partials) -> pass_b_h -> spw_t(+xq) -> pass_d_uq
//               -> gemm_expT (gated epilogue) -> gemm_out
// Round 6: GEMMs back to 128x128/acc[4][4]; A fragments read DIRECT from
// global (L2-resident weights, per-lane strided 16B) — LDS stages only B.
// Diagnosis: staged GEMM was LDS-pipe-bound (96KB/CU-round = 750cy vs
// 160cy MFMA; round-5 occupancy fix proved occupancy wasn't binding).
// ---------------------------------------------------------------------------

#define HW 4096
typedef unsigned short ushort_t;
typedef __attribute__((ext_vector_type(8))) short bf16x8;
typedef __attribute__((ext_vector_type(4))) float floatx4;

__device__ __forceinline__ ushort_t f2bf(float f) {
    unsigned u = __float_as_uint(f);
    u += 0x7FFF + ((u >> 16) & 1);           // RNE
    return (ushort_t)(u >> 16);
}
__device__ __forceinline__ float bf2f(ushort_t h) {
    return __uint_as_float(((unsigned)h) << 16);
}

__device__ __forceinline__ int cnt1f(int y, int sh, int kh, int win) {
    int t = y - kh + sh;
    int lo = t > 0 ? t / sh : 0;
    int hi = min(win - 1, y / sh);
    return hi - lo + 1;
}

__device__ __forceinline__ float posval(int f) {
    int row = f >> 8, col = f & 255;
    int a = row >> 6, b = row & 63;
    int g = col >> 6, k = col & 63;
    float omega = expf(-(float)k * (9.2103403719761836f / 64.f)); // 10000^(-k/64)
    float arg = (g < 2 ? (float)a : (float)b) * omega;
    return (g & 1) ? cosf(arg) : sinf(arg);
}

// ---------------- prep_all: pos/posT (+posbar partials), trans_x (+xbar
// partials), conv_bf16, prep_g, prep_wcomb, zero xq/posq, weight transposes.
// 15,027 blocks x 256 threads.
__global__ __launch_bounds__(256) void prep_all(
    const float* __restrict__ x, const float* __restrict__ W_exp,
    const float* __restrict__ b_exp, const float* __restrict__ wq,
    const float* __restrict__ wq_b, const float* __restrict__ W_fus,
    const float* __restrict__ W_res, const float* __restrict__ b_res,
    const float* __restrict__ b_fus, const float* __restrict__ sp_wq_w,
    const float* __restrict__ ch_wv_w, const float* __restrict__ ch_wz_w,
    float* __restrict__ pos, float* __restrict__ posT,
    ushort_t* __restrict__ xbT, ushort_t* __restrict__ wexpb,
    float* __restrict__ g, float* __restrict__ c0out,
    ushort_t* __restrict__ Wcat, float* __restrict__ biasc,
    float* __restrict__ zeroreg,
    float* __restrict__ W_expT, float* __restrict__ swqT,
    float* __restrict__ chvT, float* __restrict__ chzT,
    float* __restrict__ xpa, float* __restrict__ xp6,
    float* __restrict__ ppa, float* __restrict__ pp6)
{
    __shared__ float smf[1184];
    __shared__ float wred[8];
    int b = blockIdx.x, tid = threadIdx.x;
    if (b < 4096) {
        int idx = b * 256 + tid;
        float pv = posval(idx);
        pos[idx] = pv;
        int p2 = idx >> 8, c2 = idx & 255;
        posT[idx] = posval(c2 * 4096 + p2);
        // posbar partials: idx = c*4096 + p -> c = b>>4, p = (b&15)*256+tid
        int p = ((b & 15) << 8) + tid;
        int y = p >> 6, xx = p & 63;
        float cf = (float)(cnt1f(y, 10, 14, 6) * cnt1f(xx, 10, 14, 6));
        float s1 = pv, s2 = cf * pv;
        #pragma unroll
        for (int d = 32; d; d >>= 1) {
            s1 += __shfl_down(s1, d, 64);
            s2 += __shfl_down(s2, d, 64);
        }
        if ((tid & 63) == 0) { wred[tid >> 6] = s1; wred[4 + (tid >> 6)] = s2; }
        __syncthreads();
        if (tid == 0) {
            int slot = (b & 15) * 256 + (b >> 4);
            ppa[slot] = wred[0] + wred[1] + wred[2] + wred[3];
            pp6[slot] = wred[4] + wred[5] + wred[6] + wred[7];
        }
    } else if (b < 12288) {
        int v = b - 4096;
        int p0 = (v & 127) * 32, c0 = ((v >> 7) & 7) * 32, n = v >> 10;
        int cc = tid >> 3, p4 = (tid & 7) * 4;
        const float* src = x + (((size_t)(n * 256 + c0 + cc)) << 12) + p0 + p4;
        float4 vv = *(const float4*)src;
        // xbar partials (win=6 weighted + unweighted), 8-lane shuffle reduce
        int pg = p0 + p4;
        int y = pg >> 6, xx = pg & 63;
        float cy = (float)cnt1f(y, 10, 14, 6);
        float s6 = cy * ((float)cnt1f(xx, 10, 14, 6) * vv.x
                       + (float)cnt1f(xx + 1, 10, 14, 6) * vv.y
                       + (float)cnt1f(xx + 2, 10, 14, 6) * vv.z
                       + (float)cnt1f(xx + 3, 10, 14, 6) * vv.w);
        float s = vv.x + vv.y + vv.z + vv.w;
        #pragma unroll
        for (int d = 4; d; d >>= 1) {
            s += __shfl_down(s, d, 8);
            s6 += __shfl_down(s6, d, 8);
        }
        if ((tid & 7) == 0) {
            int pblk = v & 127;
            xpa[pblk * 2048 + n * 256 + c0 + cc] = s;
            xp6[pblk * 2048 + n * 256 + c0 + cc] = s6;
        }
        smf[cc * 37 + p4] = vv.x; smf[cc * 37 + p4 + 1] = vv.y;
        smf[cc * 37 + p4 + 2] = vv.z; smf[cc * 37 + p4 + 3] = vv.w;
        __syncthreads();
        int pp = tid >> 3, c4 = (tid & 7) * 4;
        unsigned lo = (unsigned)f2bf(smf[c4 * 37 + pp]) | ((unsigned)f2bf(smf[(c4 + 1) * 37 + pp]) << 16);
        unsigned hi = (unsigned)f2bf(smf[(c4 + 2) * 37 + pp]) | ((unsigned)f2bf(smf[(c4 + 3) * 37 + pp]) << 16);
        *(uint2*)&xbT[(((size_t)(n << 12)) + p0 + pp) * 256 + c0 + c4] = make_uint2(lo, hi);
    } else if (b < 13056) {
        int i = (b - 12288) * 256 + tid;
        wexpb[i] = f2bf(W_exp[i]);
    } else if (b < 13059) {
        int i = b - 13056;
        float* wql = smf;          // 256
        float* red = smf + 256;    // 256
        wql[tid] = wq[tid];
        red[tid] = wq[tid] * b_exp[i * 256 + tid];
        __syncthreads();
        const float* Wb = W_exp + ((size_t)(i * 256)) * 256 + tid;
        float acc = 0.f;
        #pragma unroll 8
        for (int oc = 0; oc < 256; ++oc) acc = fmaf(wql[oc], Wb[(size_t)oc * 256], acc);
        g[i * 256 + tid] = acc;
        for (int s = 128; s > 0; s >>= 1) { if (tid < s) red[tid] += red[tid + s]; __syncthreads(); }
        if (tid == 0) c0out[i] = red[0] + wq_b[0];
    } else if (b < 13827) {
        int v = b - 13059;
        int o = v & 255, jb = v >> 8;
        float* wrow = smf;         // 256
        float* red = smf + 256;    // 256
        wrow[tid] = W_fus[o * 256 + tid];
        __syncthreads();
        int j = jb * 256 + tid;
        float acc = 0.f;
        #pragma unroll 8
        for (int c = 0; c < 256; ++c) acc = fmaf(wrow[c], W_res[(size_t)c * 768 + j], acc);
        Wcat[o * 1024 + 256 + j] = f2bf(acc);
        if (jb == 0) {
            Wcat[o * 1024 + tid] = f2bf(wrow[tid]);
            red[tid] = wrow[tid] * b_res[tid];
            __syncthreads();
            for (int s = 128; s > 0; s >>= 1) { if (tid < s) red[tid] += red[tid + s]; __syncthreads(); }
            if (tid == 0) biasc[o] = red[0] + b_fus[o];
        }
    } else if (b < 13875) {
        int i = (b - 13827) * 256 + tid;   // < 12288 (xq ++ posq)
        zeroreg[i] = 0.f;
    } else if (b < 14643) {                // W_expT[c][r] = W_exp[r][c]  (768x256)
        int idx = (b - 13875) * 256 + tid;
        W_expT[(idx & 255) * 768 + (idx >> 8)] = W_exp[idx];
    } else if (b < 14771) {                // swqT[c][q] (128x256 src)
        int idx = (b - 14643) * 256 + tid;
        swqT[(idx & 255) * 128 + (idx >> 8)] = sp_wq_w[idx];
    } else if (b < 14899) {                // chvT[c][q] (128x256 src)
        int idx = (b - 14771) * 256 + tid;
        chvT[(idx & 255) * 128 + (idx >> 8)] = ch_wv_w[idx];
    } else {                               // chzT[c2][o] (256x128 src)
        int idx = (b - 14899) * 256 + tid;
        chzT[(idx & 127) * 256 + (idx >> 7)] = ch_wz_w[idx];
    }
}

// ---- blocks 0..511: qdot (512 thr, 64 p each, 8-way k-split) + single-wave
//      softmax partials. blocks 512..535: ubar (finalizes xbar/posbar).
__global__ __launch_bounds__(512) void qdot_ubar(
    const float* __restrict__ x, const float* __restrict__ pos,
    const float* __restrict__ g, const float* __restrict__ c0in,
    const float* __restrict__ wq, float* __restrict__ qdot,
    const float* __restrict__ b_exp,
    const float* __restrict__ xpa, const float* __restrict__ xp6,
    const float* __restrict__ ppa, const float* __restrict__ pp6,
    const float* __restrict__ W_expT, float* __restrict__ ubar,
    float* __restrict__ qpm, float* __restrict__ qpz)
{
    int blk = blockIdx.x, tid = threadIdx.x;
    if (blk < 512) {
        int n = blk >> 6;
        int ph = tid & 63, cq = tid >> 6;          // 8 c-groups of 32
        int pb = blk & 63;
        int p = pb * 64 + ph;
        __shared__ float gl[768];
        __shared__ float wql[256];
        __shared__ float4 red4[512];
        for (int k = tid; k < 768; k += 512) gl[k] = g[k];
        if (tid < 256) wql[tid] = wq[tid];
        __syncthreads();
        const float* xp = x + (((size_t)n) << 20) + p;
        const float* pp = pos + p;
        float q0 = 0.f, q1 = 0.f, q2 = 0.f, qp = 0.f;
        #pragma unroll 4
        for (int c = cq * 32; c < cq * 32 + 32; ++c) {
            float xv = xp[(size_t)c << 12];
            float pv = pp[(size_t)c << 12];
            q0 = fmaf(gl[c], xv, q0);
            q1 = fmaf(gl[256 + c], xv, q1);
            q2 = fmaf(gl[512 + c], xv, q2);
            qp = fmaf(wql[c], pv, qp);
        }
        red4[tid] = make_float4(q0, q1, q2, qp);
        __syncthreads();
        if (tid < 64) {
            float sx = 0.f, sy = 0.f, sz = 0.f, sw = 0.f;
            #pragma unroll
            for (int k = 0; k < 8; ++k) {
                float4 t4 = red4[k * 64 + tid];
                sx += t4.x; sy += t4.y; sz += t4.z; sw += t4.w;
            }
            float va = sx + sw + c0in[0];
            float vb = sy + sw + c0in[1];
            float vc = sz + sw + c0in[2];
            qdot[((0 * 8 + n) << 12) + p] = va;
            qdot[((1 * 8 + n) << 12) + p] = vb;
            qdot[((2 * 8 + n) << 12) + p] = vc;
            // single-wave softmax partials over the 64 p's
            float vv[3] = {va, vb, vc};
            int y = p >> 6, xx = p & 63;
            #pragma unroll
            for (int i = 0; i < 3; ++i) {
                int win = 2 * (i + 1), sh = 64 / win, kh = sh + 64 % win;
                float cf = (float)(cnt1f(y, sh, kh, win) * cnt1f(xx, sh, kh, win));
                float m = vv[i];
                #pragma unroll
                for (int d2 = 32; d2; d2 >>= 1) m = fmaxf(m, __shfl_down(m, d2, 64));
                m = __shfl(m, 0, 64);
                float z = cf * expf(vv[i] - m);
                #pragma unroll
                for (int d2 = 32; d2; d2 >>= 1) z += __shfl_down(z, d2, 64);
                if (tid == 0) {
                    int bidx = (i * 8 + n) * 64 + pb;
                    qpm[bidx] = m; qpz[bidx] = z;
                }
            }
        }
    } else {
        int v = blk - 512;
        int i = v >> 3, n = v & 7;
        __shared__ float xbl[256];
        if (tid < 256) {
            const float* xp_ = (i < 2) ? xpa : xp6;
            float s = 0.f;
            #pragma unroll 8
            for (int k = 0; k < 128; ++k) s += xp_[k * 2048 + n * 256 + tid];
            xbl[tid] = s;
        }
        __syncthreads();
        if (tid < 256) {
            const float* pp_ = (i < 2) ? ppa : pp6;
            float pb = 0.f;
            #pragma unroll
            for (int k = 0; k < 16; ++k) pb += pp_[k * 256 + tid];
            int win = 2 * (i + 1), sh = 64 / win, kh = sh + 64 % win;
            float Li = (float)(win * win * kh * kh);
            float acc = b_exp[i * 256 + tid] * Li + pb;
            const float* Wc = W_expT + i * 256 + tid;
            #pragma unroll 8
            for (int j = 0; j < 256; ++j) acc = fmaf(Wc[(size_t)j * 768], xbl[j], acc);
            ubar[(i * 8 + n) * 256 + tid] = acc;
        }
    }
}

// ---- merge softmax partials, spq, w_eff, h, btot (grid 3 x 8)
__global__ __launch_bounds__(256) void pass_b_h(
    const float* __restrict__ ubar_raw,
    const float* __restrict__ swqT, const float* __restrict__ sp_wq_b,
    const float* __restrict__ sp_wv_w, const float* __restrict__ sp_wv_b,
    const float* __restrict__ W_exp, const float* __restrict__ b_exp,
    const float* __restrict__ qpm, const float* __restrict__ qpz,
    float* __restrict__ Mn, float* __restrict__ invZn,
    float* __restrict__ w_eff, float* __restrict__ h, float* __restrict__ btot)
{
    int i = blockIdx.x, n = blockIdx.y, tid = threadIdx.x;
    int b = i * 8 + n;
    int win = 2 * (i + 1), sh = 64 / win, kh = sh + 64 % win;
    float invL = 1.f / (float)(win * win * kh * kh);
    __shared__ float red[256];
    __shared__ float ub[256];
    __shared__ float spq[128];
    __shared__ float we[256];
    // merge the 64 per-block (m,z) partials (wave 0 only)
    if (tid < 64) {
        float mp = qpm[b * 64 + tid];
        float zp = qpz[b * 64 + tid];
        float mm = mp;
        #pragma unroll
        for (int d = 32; d; d >>= 1) mm = fmaxf(mm, __shfl_down(mm, d, 64));
        float M = __shfl(mm, 0, 64);
        float zz = zp * expf(mp - M);
        #pragma unroll
        for (int d = 32; d; d >>= 1) zz += __shfl_down(zz, d, 64);
        if (tid == 0) { Mn[b] = M; invZn[b] = 1.f / zz; }
    }
    ub[tid] = ubar_raw[b * 256 + tid] * invL;
    __syncthreads();
    float sl = -1e30f;
    if (tid < 128) {
        float a = sp_wq_b[tid];
        #pragma unroll 8
        for (int c = 0; c < 256; ++c) a = fmaf(swqT[c * 128 + tid], ub[c], a);
        sl = a;
    }
    red[tid] = sl; __syncthreads();
    for (int s = 128; s > 0; s >>= 1) { if (tid < s) red[tid] = fmaxf(red[tid], red[tid + s]); __syncthreads(); }
    float m2 = red[0]; __syncthreads();
    float e = (tid < 128) ? expf(sl - m2) : 0.f;
    red[tid] = e; __syncthreads();
    for (int s = 128; s > 0; s >>= 1) { if (tid < s) red[tid] += red[tid + s]; __syncthreads(); }
    float S2 = red[0]; __syncthreads();
    if (tid < 128) spq[tid] = e / S2;
    __syncthreads();
    float a = 0.f;
    #pragma unroll 8
    for (int c2 = 0; c2 < 128; ++c2) a = fmaf(spq[c2], sp_wv_w[c2 * 256 + tid], a);
    w_eff[b * 256 + tid] = a;
    we[tid] = a;
    red[tid] = (tid < 128) ? spq[tid] * sp_wv_b[tid] : 0.f;
    __syncthreads();
    for (int s = 128; s > 0; s >>= 1) { if (tid < s) red[tid] += red[tid + s]; __syncthreads(); }
    float beff = red[0]; __syncthreads();
    const float* Wb = W_exp + (size_t)i * 65536 + tid;
    float hacc = 0.f;
    #pragma unroll 8
    for (int oc = 0; oc < 256; ++oc) hacc = fmaf(we[oc], Wb[(size_t)oc * 256], hacc);
    h[b * 256 + tid] = hacc;
    red[tid] = we[tid] * b_exp[i * 256 + tid];
    __syncthreads();
    for (int s = 128; s > 0; s >>= 1) { if (tid < s) red[tid] += red[tid + s]; __syncthreads(); }
    if (tid == 0) btot[b] = red[0] + beff;
}

// --- phase1: spw = sigmoid(h.x + weff.pos + btot), t = cnt*softmax(qdot)
// --- phase2: xq[c]  += sum_p t*xbT[p][c]  (bf16), posq[c] += sum_p t*posT[p][c]
// 64 p per block (2x grid vs round 2 for occupancy).
__global__ __launch_bounds__(512) void spw_t_xq(
    const float* __restrict__ x, const float* __restrict__ pos,
    const float* __restrict__ h, const float* __restrict__ weff,
    const float* __restrict__ qdot, const float* __restrict__ Mn,
    const float* __restrict__ invZn, const float* __restrict__ btot,
    const ushort_t* __restrict__ xbT, const float* __restrict__ posT,
    float* __restrict__ spw, float* __restrict__ xq, float* __restrict__ posq)
{
    int n = blockIdx.y, tid = threadIdx.x;
    int ph = tid & 63, cq = tid >> 6;              // 8 c-groups of 32
    int p0b = blockIdx.x * 64;
    int p = p0b + ph;
    __shared__ float hl[768], wl[768];
    __shared__ float4 red4[512];
    __shared__ float tl[3][64];
    for (int k = tid; k < 768; k += 512) {
        int i = k >> 8, c = k & 255;
        hl[k] = h[(i * 8 + n) * 256 + c];
        wl[k] = weff[(i * 8 + n) * 256 + c];
    }
    __syncthreads();
    const float* xp = x + (((size_t)n) << 20) + p;
    const float* pp = pos + p;
    float a0 = 0.f, a1 = 0.f, a2 = 0.f;
    #pragma unroll 4
    for (int c = cq * 32; c < cq * 32 + 32; ++c) {
        float xv = xp[(size_t)c << 12];
        float pv = pp[(size_t)c << 12];
        a0 += hl[c] * xv + wl[c] * pv;
        a1 += hl[256 + c] * xv + wl[256 + c] * pv;
        a2 += hl[512 + c] * xv + wl[512 + c] * pv;
    }
    red4[tid] = make_float4(a0, a1, a2, 0.f);
    __syncthreads();
    if (tid < 64) {
        float sx = 0.f, sy = 0.f, sz = 0.f;
        #pragma unroll
        for (int k = 0; k < 8; ++k) {
            float4 t4 = red4[k * 64 + tid];
            sx += t4.x; sy += t4.y; sz += t4.z;
        }
        float av[3] = {sx, sy, sz};
        int y = p >> 6, xx = p & 63;
        #pragma unroll
        for (int i = 0; i < 3; ++i) {
            int b = i * 8 + n;
            int win = 2 * (i + 1), sh = 64 / win, kh = sh + 64 % win;
            float cf = (float)(cnt1f(y, sh, kh, win) * cnt1f(xx, sh, kh, win));
            int idx = (b << 12) + p;
            spw[idx] = 1.f / (1.f + expf(-(av[i] + btot[b])));
            tl[i][ph] = cf * expf(qdot[idx] - Mn[b]) * invZn[b];
        }
    }
    __syncthreads();
    // phase 2
    int c = tid & 255;
    int half = tid >> 8;
    float s0 = 0.f, s1 = 0.f, s2 = 0.f;
    if (half == 0) {
        const ushort_t* xb = xbT + (((size_t)((n << 12) + p0b)) << 8) + c;
        #pragma unroll 4
        for (int pl = 0; pl < 64; ++pl) {
            float xv = bf2f(xb[(size_t)pl << 8]);
            s0 = fmaf(tl[0][pl], xv, s0);
            s1 = fmaf(tl[1][pl], xv, s1);
            s2 = fmaf(tl[2][pl], xv, s2);
        }
        atomicAdd(&xq[(0 * 8 + n) * 256 + c], s0);
        atomicAdd(&xq[(1 * 8 + n) * 256 + c], s1);
        atomicAdd(&xq[(2 * 8 + n) * 256 + c], s2);
    } else {
        const float* pt = posT + (((size_t)p0b) << 8) + c;
        #pragma unroll 4
        for (int pl = 0; pl < 64; ++pl) {
            float pv = pt[(size_t)pl << 8];
            s0 = fmaf(tl[0][pl], pv, s0);
            s1 = fmaf(tl[1][pl], pv, s1);
            s2 = fmaf(tl[2][pl], pv, s2);
        }
        atomicAdd(&posq[(0 * 8 + n) * 256 + c], s0);
        atomicAdd(&posq[(1 * 8 + n) * 256 + c], s1);
        atomicAdd(&posq[(2 * 8 + n) * 256 + c], s2);
    }
}

// ---- uq = W_exp_i@xq + b + posq; z->wz->LN->sigmoid->chw (grid 3x8)
__global__ __launch_bounds__(256) void pass_d_uq(
    const float* __restrict__ W_expT, const float* __restrict__ b_exp,
    const float* __restrict__ xq, const float* __restrict__ posq,
    const float* __restrict__ chvT, const float* __restrict__ ch_wv_b,
    const float* __restrict__ chzT, const float* __restrict__ ch_wz_b,
    const float* __restrict__ ln_g, const float* __restrict__ ln_b,
    float* __restrict__ ch_w)
{
    int i = blockIdx.x, n = blockIdx.y, tid = threadIdx.x;
    int b = i * 8 + n;
    __shared__ float xql[256];
    __shared__ float uql[256];
    __shared__ float zz[128];
    __shared__ float red[256];
    xql[tid] = xq[b * 256 + tid];
    __syncthreads();
    float acc = b_exp[i * 256 + tid] + posq[b * 256 + tid];
    const float* Wc = W_expT + i * 256 + tid;
    #pragma unroll 8
    for (int cin = 0; cin < 256; ++cin) acc = fmaf(Wc[(size_t)cin * 768], xql[cin], acc);
    uql[tid] = acc;
    __syncthreads();
    if (tid < 128) {
        float a = ch_wv_b[tid];
        #pragma unroll 8
        for (int c = 0; c < 256; ++c) a = fmaf(chvT[c * 128 + tid], uql[c], a);
        zz[tid] = a;
    }
    __syncthreads();
    float wz = ch_wz_b[tid];
    #pragma unroll 8
    for (int c2 = 0; c2 < 128; ++c2) wz = fmaf(chzT[c2 * 256 + tid], zz[c2], wz);
    red[tid] = wz; __syncthreads();
    for (int s = 128; s > 0; s >>= 1) { if (tid < s) red[tid] += red[tid + s]; __syncthreads(); }
    float mean = red[0] * (1.f / 256.f); __syncthreads();
    float d = wz - mean;
    red[tid] = d * d; __syncthreads();
    for (int s = 128; s > 0; s >>= 1) { if (tid < s) red[tid] += red[tid + s]; __syncthreads(); }
    float var = red[0] * (1.f / 256.f);
    float xn = d / sqrtf(var + 1e-5f);
    ch_w[b * 256 + tid] = 1.f / (1.f + expf(-(xn * ln_g[tid] + ln_b[tid])));
}

// ---- MFMA GEMM 1 (A direct-from-global, B LDS-staged, gated epilogue):
//   exT bf16 [n][p][768];  e = W_exp@x+b;  combined = e + (e+posT)*(chw+spw)
__global__ __launch_bounds__(256) void gemm_expT(
    const ushort_t* __restrict__ Wb, const ushort_t* __restrict__ XT,
    const float* __restrict__ bias, const float* __restrict__ posT,
    const float* __restrict__ chw, const float* __restrict__ spw,
    ushort_t* __restrict__ OutT)
{
    __shared__ ushort_t SM[10240];           // Bs [128][40] ; reused as stage [128][72]
    int n = blockIdx.z;
    int p0 = blockIdx.x * 128;
    int o0 = blockIdx.y * 128;
    int t = threadIdx.x;
    int lane = t & 63, wave = t >> 6;
    int wm = (wave & 1) * 64, wn = (wave >> 1) * 64;
    int lr = lane & 15, lk = (lane >> 4) * 8;
    int ar = t >> 2, ac = (t & 3) * 8;
    // A fragments direct from global: lane reads row o0+wm+mi*16+lr, k = k0+lk..+7.
    // lanes l, l+16, l+32, l+48 share a row and cover 64B contiguous k.
    const ushort_t* Ag = Wb + (size_t)(o0 + wm + lr) * 256 + lk;
    const ushort_t* B0 = XT + (((size_t)(n << 12)) + p0 + ar) * 256 + ac;
    const ushort_t* B1 = XT + (((size_t)(n << 12)) + p0 + ar + 64) * 256 + ac;
    floatx4 acc[4][4] = {};
    for (int k0 = 0; k0 < 256; k0 += 32) {
        uint4 b0 = *(const uint4*)(B0 + k0);
        uint4 b1 = *(const uint4*)(B1 + k0);
        __syncthreads();
        *(uint4*)&SM[ar * 40 + ac] = b0;
        *(uint4*)&SM[(ar + 64) * 40 + ac] = b1;
        __syncthreads();
        bf16x8 af[4], bfr[4];
        #pragma unroll
        for (int mi = 0; mi < 4; ++mi)
            af[mi] = *(const bf16x8*)(Ag + mi * 16 * 256 + k0);
        #pragma unroll
        for (int ni = 0; ni < 4; ++ni)
            bfr[ni] = *(const bf16x8*)&SM[(wn + ni * 16 + lr) * 40 + lk];
        #pragma unroll
        for (int mi = 0; mi < 4; ++mi)
            #pragma unroll
            for (int ni = 0; ni < 4; ++ni)
                acc[mi][ni] = __builtin_amdgcn_mfma_f32_16x16x32_bf16(
                    af[mi], bfr[ni], acc[mi][ni], 0, 0, 0);
    }
    int col = lane & 15, rb = (lane >> 4) * 4;
    int ibr = o0 >> 8;
    int bi = ibr * 8 + n;
    #pragma unroll
    for (int r = 0; r < 2; ++r) {
        __syncthreads();
        if (wm == r * 64) {
            #pragma unroll
            for (int mi = 0; mi < 4; ++mi) {
                int o_loc = mi * 16 + rb;
                float4 bo = *(const float4*)&bias[o0 + r * 64 + o_loc];
                #pragma unroll
                for (int ni = 0; ni < 4; ++ni) {
                    int prow = wn + ni * 16 + col;
                    floatx4 v = acc[mi][ni];
                    unsigned lo = (unsigned)f2bf(v[0] + bo.x) | ((unsigned)f2bf(v[1] + bo.y) << 16);
                    unsigned hi = (unsigned)f2bf(v[2] + bo.z) | ((unsigned)f2bf(v[3] + bo.w) << 16);
                    *(uint2*)&SM[prow * 72 + o_loc] = make_uint2(lo, hi);
                }
            }
        }
        __syncthreads();
        #pragma unroll
        for (int it = 0; it < 4; ++it) {
            int slot = it * 256 + t;
            int pl = slot >> 3, j = (slot & 7) * 8;
            uint4 raw = *(const uint4*)&SM[pl * 72 + j];
            float e0 = bf2f((ushort_t)(raw.x & 0xFFFF)), e1 = bf2f((ushort_t)(raw.x >> 16));
            float e2 = bf2f((ushort_t)(raw.y & 0xFFFF)), e3 = bf2f((ushort_t)(raw.y >> 16));
            float e4 = bf2f((ushort_t)(raw.z & 0xFFFF)), e5 = bf2f((ushort_t)(raw.z >> 16));
            float e6 = bf2f((ushort_t)(raw.w & 0xFFFF)), e7 = bf2f((ushort_t)(raw.w >> 16));
            int p = p0 + pl;
            int cbase = (o0 & 255) + r * 64 + j;
            float s = spw[(bi << 12) + p];
            float4 q0 = *(const float4*)&posT[p * 256 + cbase];
            float4 q1 = *(const float4*)&posT[p * 256 + cbase + 4];
            float4 w0 = *(const float4*)&chw[bi * 256 + cbase];
            float4 w1 = *(const float4*)&chw[bi * 256 + cbase + 4];
            float r0 = e0 + (e0 + q0.x) * (w0.x + s);
            float r1 = e1 + (e1 + q0.y) * (w0.y + s);
            float r2 = e2 + (e2 + q0.z) * (w0.z + s);
            float r3 = e3 + (e3 + q0.w) * (w0.w + s);
            float r4 = e4 + (e4 + q1.x) * (w1.x + s);
            float r5 = e5 + (e5 + q1.y) * (w1.y + s);
            float r6 = e6 + (e6 + q1.z) * (w1.z + s);
            float r7 = e7 + (e7 + q1.w) * (w1.w + s);
            uint4 outv;
            outv.x = (unsigned)f2bf(r0) | ((unsigned)f2bf(r1) << 16);
            outv.y = (unsigned)f2bf(r2) | ((unsigned)f2bf(r3) << 16);
            outv.z = (unsigned)f2bf(r4) | ((unsigned)f2bf(r5) << 16);
            outv.w = (unsigned)f2bf(r6) | ((unsigned)f2bf(r7) << 16);
            *(uint4*)&OutT[(((size_t)(n << 12)) + p) * 768 + o0 + r * 64 + j] = outv;
        }
    }
}

// ---- MFMA GEMM 2 (A direct-from-global, B LDS-staged):
//   out = Wcat @ [x ; combined] + biasc, fp32 [n][256][4096]
__global__ __launch_bounds__(256) void gemm_out(
    const ushort_t* __restrict__ Wcat, const ushort_t* __restrict__ XT,
    const ushort_t* __restrict__ CT, const float* __restrict__ biasc,
    float* __restrict__ Out)
{
    __shared__ ushort_t Bs[128 * 40];
    int n = blockIdx.z;
    int p0 = blockIdx.x * 128;
    int o0 = blockIdx.y * 128;
    int t = threadIdx.x;
    int lane = t & 63, wave = t >> 6;
    int wm = (wave & 1) * 64, wn = (wave >> 1) * 64;
    int lr = lane & 15, lk = (lane >> 4) * 8;
    int ar = t >> 2, ac = (t & 3) * 8;
    const ushort_t* Ag = Wcat + (size_t)(o0 + wm + lr) * 1024 + lk;
    const ushort_t* BX0 = XT + (((size_t)(n << 12)) + p0 + ar) * 256 + ac;
    const ushort_t* BX1 = XT + (((size_t)(n << 12)) + p0 + ar + 64) * 256 + ac;
    const ushort_t* BC0 = CT + (((size_t)(n << 12)) + p0 + ar) * 768 + ac;
    const ushort_t* BC1 = CT + (((size_t)(n << 12)) + p0 + ar + 64) * 768 + ac;
    floatx4 acc[4][4] = {};
    for (int k0 = 0; k0 < 1024; k0 += 32) {
        const ushort_t* pb0 = (k0 < 256) ? (BX0 + k0) : (BC0 + (k0 - 256));
        const ushort_t* pb1 = (k0 < 256) ? (BX1 + k0) : (BC1 + (k0 - 256));
        uint4 b0 = *(const uint4*)pb0;
        uint4 b1 = *(const uint4*)pb1;
        __syncthreads();
        *(uint4*)&Bs[ar * 40 + ac] = b0;
        *(uint4*)&Bs[(ar + 64) * 40 + ac] = b1;
        __syncthreads();
        bf16x8 af[4], bfr[4];
        #pragma unroll
        for (int mi = 0; mi < 4; ++mi)
            af[mi] = *(const bf16x8*)(Ag + mi * 16 * 1024 + k0);
        #pragma unroll
        for (int ni = 0; ni < 4; ++ni)
            bfr[ni] = *(const bf16x8*)&Bs[(wn + ni * 16 + lr) * 40 + lk];
        #pragma unroll
        for (int mi = 0; mi < 4; ++mi)
            #pragma unroll
            for (int ni = 0; ni < 4; ++ni)
                acc[mi][ni] = __builtin_amdgcn_mfma_f32_16x16x32_bf16(
                    af[mi], bfr[ni], acc[mi][ni], 0, 0, 0);
    }
    int col = lane & 15, rb = (lane >> 4) * 4;
    #pragma unroll
    for (int mi = 0; mi < 4; ++mi) {
        int o = o0 + wm + mi * 16 + rb;
        float4 bo = *(const float4*)&biasc[o];
        #pragma unroll
        for (int r = 0; r < 4; ++r) {
            float br = (r == 0) ? bo.x : (r == 1) ? bo.y : (r == 2) ? bo.z : bo.w;
            #pragma unroll
            for (int ni = 0; ni < 4; ++ni) {
                int p = p0 + wn + ni * 16 + col;
                Out[(((size_t)(n * 256 + o + r)) << 12) + p] = acc[mi][ni][r] + br;
            }
        }
    }
}

// ---------------------------------------------------------------------------
extern "C" void kernel_launch(void* const* d_in, const int* in_sizes, int n_in,
                              void* d_out, int out_size, void* d_ws, size_t ws_size,
                              hipStream_t stream) {
    const float* x        = (const float*)d_in[0];
    const float* w_exp    = (const float*)d_in[1];
    const float* b_exp    = (const float*)d_in[2];
    const float* w_res    = (const float*)d_in[3];
    const float* b_res    = (const float*)d_in[4];
    const float* w_fus    = (const float*)d_in[5];
    const float* b_fus    = (const float*)d_in[6];
    const float* ch_wv_w  = (const float*)d_in[7];
    const float* ch_wv_b  = (const float*)d_in[8];
    const float* ch_wq_w  = (const float*)d_in[9];
    const float* ch_wq_b  = (const float*)d_in[10];
    const float* ch_wz_w  = (const float*)d_in[11];
    const float* ch_wz_b  = (const float*)d_in[12];
    const float* ln_g     = (const float*)d_in[13];
    const float* ln_b     = (const float*)d_in[14];
    const float* sp_wv_w  = (const float*)d_in[15];
    const float* sp_wv_b  = (const float*)d_in[16];
    const float* sp_wq_w  = (const float*)d_in[17];
    const float* sp_wq_b  = (const float*)d_in[18];
    float* out = (float*)d_out;
    float* ws  = (float*)d_ws;

    // workspace layout (float offsets)
    float*    pos   = ws + 0;                      // 1,048,576
    float*    posT  = ws + 1048576;                // 1,048,576
    ushort_t* xbT   = (ushort_t*)(ws + 2097152);   // 8,388,608 ushorts
    ushort_t* exT   = (ushort_t*)(ws + 6291456);   // 25,165,824 ushorts
    ushort_t* wexpb = (ushort_t*)(ws + 18874368);  // 196,608 ushorts
    ushort_t* Wcat  = (ushort_t*)(ws + 18972672);  // 262,144 ushorts
    float*    qdot  = ws + 19103744;   // 98,304
    float*    spw   = ws + 19300352;   // 98,304
    float*    g     = ws + 19398656;   // 768
    float*    c0v   = ws + 19399424;   // 4
    float*    ubar  = ws + 19399428;   // 6,144
    float*    Mn    = ws + 19410180;   // 24
    float*    iZ    = ws + 19410204;   // 24
    float*    weff  = ws + 19410228;   // 6,144
    float*    btot  = ws + 19416372;   // 24
    float*    hb    = ws + 19416396;   // 6,144
    float*    xq    = ws + 19422540;   // 6,144  (zeroed in prep_all)
    float*    posq  = ws + 19428684;   // 6,144  (zeroed in prep_all)
    float*    chw   = ws + 19434828;   // 6,144
    float*    biasc = ws + 19440972;   // 256
    float*    W_expT = ws + 19441228;  // 196,608
    float*    swqT   = ws + 19637836;  // 32,768
    float*    chvT   = ws + 19670604;  // 32,768
    float*    chzT   = ws + 19703372;  // 32,768
    float*    xpa    = ws + 19736140;  // 262,144 (128 pblk x [n*256+c])
    float*    xp6    = ws + 19998284;  // 262,144
    float*    ppa    = ws + 20260428;  // 4,096 (16 slots x 256 c)
    float*    pp6    = ws + 20264524;  // 4,096
    float*    qpm    = ws + 20268620;  // 1,536 (3*8*64 softmax partial max)
    float*    qpz    = ws + 20270156;  // 1,536 (partial expsum)

    prep_all<<<15027, 256, 0, stream>>>(x, w_exp, b_exp, ch_wq_w, ch_wq_b,
                                        w_fus, w_res, b_res, b_fus,
                                        sp_wq_w, ch_wv_w, ch_wz_w,
                                        pos, posT, xbT, wexpb, g, c0v,
                                        Wcat, biasc, xq,
                                        W_expT, swqT, chvT, chzT,
                                        xpa, xp6, ppa, pp6);
    qdot_ubar<<<536, 512, 0, stream>>>(x, pos, g, c0v, ch_wq_w, qdot,
                                       b_exp, xpa, xp6, ppa, pp6, W_expT, ubar,
                                       qpm, qpz);
    pass_b_h<<<dim3(3, 8), 256, 0, stream>>>(ubar, swqT, sp_wq_b,
                                             sp_wv_w, sp_wv_b, w_exp, b_exp,
                                             qpm, qpz,
                                             Mn, iZ, weff, hb, btot);
    spw_t_xq<<<dim3(64, 8), 512, 0, stream>>>(x, pos, hb, weff, qdot, Mn, iZ,
                                              btot, xbT, posT, spw, xq, posq);
    pass_d_uq<<<dim3(3, 8), 256, 0, stream>>>(W_expT, b_exp, xq, posq,
                                              chvT, ch_wv_b, chzT, ch_wz_b,
                                              ln_g, ln_b, chw);
    gemm_expT<<<dim3(32, 6, 8), 256, 0, stream>>>(wexpb, xbT, b_exp, posT, chw, spw, exT);
    gemm_out<<<dim3(32, 2, 8), 256, 0, stream>>>(Wcat, xbT, exT, biasc, out);
}

// Round 8
// 258.548 us; speedup vs baseline: 1.2501x; 1.2501x over previous
//
#include <hip/hip_runtime.h>
#include <cstddef>
#include <cstdint>

// ---------------------------------------------------------------------------
// PatchAttention, algebraically simplified + bf16 MFMA GEMMs.
// 7 dispatches: prep_all (+xbar partials, +weight transposes) -> qdot+ubar
//               (+softmax partials) -> pass_b_h -> spw_t(+xq) -> pass_d_uq
//               -> gemm_expT (gated epilogue) -> gemm_out
// GEMMs: round-0 reg-staged 128x128 (measured best: r1 gload_lds-dbuf 44.5us,
// r5 small-tile 41.6us, r6 A-direct 55.7us all worse than <=40us baseline).
// Round 7/8: pass_b_h / pass_d_uq widened to 1024 threads (4-8 way k-split) —
// they ran 5 serial matvec chains on 24-block grids (24/256 CUs busy).
// (Round-7 bench was an infra failure; identical resubmit.)
// ---------------------------------------------------------------------------

#define HW 4096
typedef unsigned short ushort_t;
typedef __attribute__((ext_vector_type(8))) short bf16x8;
typedef __attribute__((ext_vector_type(4))) float floatx4;

__device__ __forceinline__ ushort_t f2bf(float f) {
    unsigned u = __float_as_uint(f);
    u += 0x7FFF + ((u >> 16) & 1);           // RNE
    return (ushort_t)(u >> 16);
}
__device__ __forceinline__ float bf2f(ushort_t h) {
    return __uint_as_float(((unsigned)h) << 16);
}

__device__ __forceinline__ int cnt1f(int y, int sh, int kh, int win) {
    int t = y - kh + sh;
    int lo = t > 0 ? t / sh : 0;
    int hi = min(win - 1, y / sh);
    return hi - lo + 1;
}

__device__ __forceinline__ float posval(int f) {
    int row = f >> 8, col = f & 255;
    int a = row >> 6, b = row & 63;
    int g = col >> 6, k = col & 63;
    float omega = expf(-(float)k * (9.2103403719761836f / 64.f)); // 10000^(-k/64)
    float arg = (g < 2 ? (float)a : (float)b) * omega;
    return (g & 1) ? cosf(arg) : sinf(arg);
}

// ---------------- prep_all: pos/posT (+posbar partials), trans_x (+xbar
// partials), conv_bf16, prep_g, prep_wcomb, zero xq/posq, weight transposes.
// 15,027 blocks x 256 threads.
__global__ __launch_bounds__(256) void prep_all(
    const float* __restrict__ x, const float* __restrict__ W_exp,
    const float* __restrict__ b_exp, const float* __restrict__ wq,
    const float* __restrict__ wq_b, const float* __restrict__ W_fus,
    const float* __restrict__ W_res, const float* __restrict__ b_res,
    const float* __restrict__ b_fus, const float* __restrict__ sp_wq_w,
    const float* __restrict__ ch_wv_w, const float* __restrict__ ch_wz_w,
    float* __restrict__ pos, float* __restrict__ posT,
    ushort_t* __restrict__ xbT, ushort_t* __restrict__ wexpb,
    float* __restrict__ g, float* __restrict__ c0out,
    ushort_t* __restrict__ Wcat, float* __restrict__ biasc,
    float* __restrict__ zeroreg,
    float* __restrict__ W_expT, float* __restrict__ swqT,
    float* __restrict__ chvT, float* __restrict__ chzT,
    float* __restrict__ xpa, float* __restrict__ xp6,
    float* __restrict__ ppa, float* __restrict__ pp6)
{
    __shared__ float smf[1184];
    __shared__ float wred[8];
    int b = blockIdx.x, tid = threadIdx.x;
    if (b < 4096) {
        int idx = b * 256 + tid;
        float pv = posval(idx);
        pos[idx] = pv;
        int p2 = idx >> 8, c2 = idx & 255;
        posT[idx] = posval(c2 * 4096 + p2);
        // posbar partials: idx = c*4096 + p -> c = b>>4, p = (b&15)*256+tid
        int p = ((b & 15) << 8) + tid;
        int y = p >> 6, xx = p & 63;
        float cf = (float)(cnt1f(y, 10, 14, 6) * cnt1f(xx, 10, 14, 6));
        float s1 = pv, s2 = cf * pv;
        #pragma unroll
        for (int d = 32; d; d >>= 1) {
            s1 += __shfl_down(s1, d, 64);
            s2 += __shfl_down(s2, d, 64);
        }
        if ((tid & 63) == 0) { wred[tid >> 6] = s1; wred[4 + (tid >> 6)] = s2; }
        __syncthreads();
        if (tid == 0) {
            int slot = (b & 15) * 256 + (b >> 4);
            ppa[slot] = wred[0] + wred[1] + wred[2] + wred[3];
            pp6[slot] = wred[4] + wred[5] + wred[6] + wred[7];
        }
    } else if (b < 12288) {
        int v = b - 4096;
        int p0 = (v & 127) * 32, c0 = ((v >> 7) & 7) * 32, n = v >> 10;
        int cc = tid >> 3, p4 = (tid & 7) * 4;
        const float* src = x + (((size_t)(n * 256 + c0 + cc)) << 12) + p0 + p4;
        float4 vv = *(const float4*)src;
        // xbar partials (win=6 weighted + unweighted), 8-lane shuffle reduce
        int pg = p0 + p4;
        int y = pg >> 6, xx = pg & 63;
        float cy = (float)cnt1f(y, 10, 14, 6);
        float s6 = cy * ((float)cnt1f(xx, 10, 14, 6) * vv.x
                       + (float)cnt1f(xx + 1, 10, 14, 6) * vv.y
                       + (float)cnt1f(xx + 2, 10, 14, 6) * vv.z
                       + (float)cnt1f(xx + 3, 10, 14, 6) * vv.w);
        float s = vv.x + vv.y + vv.z + vv.w;
        #pragma unroll
        for (int d = 4; d; d >>= 1) {
            s += __shfl_down(s, d, 8);
            s6 += __shfl_down(s6, d, 8);
        }
        if ((tid & 7) == 0) {
            int pblk = v & 127;
            xpa[pblk * 2048 + n * 256 + c0 + cc] = s;
            xp6[pblk * 2048 + n * 256 + c0 + cc] = s6;
        }
        smf[cc * 37 + p4] = vv.x; smf[cc * 37 + p4 + 1] = vv.y;
        smf[cc * 37 + p4 + 2] = vv.z; smf[cc * 37 + p4 + 3] = vv.w;
        __syncthreads();
        int pp = tid >> 3, c4 = (tid & 7) * 4;
        unsigned lo = (unsigned)f2bf(smf[c4 * 37 + pp]) | ((unsigned)f2bf(smf[(c4 + 1) * 37 + pp]) << 16);
        unsigned hi = (unsigned)f2bf(smf[(c4 + 2) * 37 + pp]) | ((unsigned)f2bf(smf[(c4 + 3) * 37 + pp]) << 16);
        *(uint2*)&xbT[(((size_t)(n << 12)) + p0 + pp) * 256 + c0 + c4] = make_uint2(lo, hi);
    } else if (b < 13056) {
        int i = (b - 12288) * 256 + tid;
        wexpb[i] = f2bf(W_exp[i]);
    } else if (b < 13059) {
        int i = b - 13056;
        float* wql = smf;          // 256
        float* red = smf + 256;    // 256
        wql[tid] = wq[tid];
        red[tid] = wq[tid] * b_exp[i * 256 + tid];
        __syncthreads();
        const float* Wb = W_exp + ((size_t)(i * 256)) * 256 + tid;
        float acc = 0.f;
        #pragma unroll 8
        for (int oc = 0; oc < 256; ++oc) acc = fmaf(wql[oc], Wb[(size_t)oc * 256], acc);
        g[i * 256 + tid] = acc;
        for (int s = 128; s > 0; s >>= 1) { if (tid < s) red[tid] += red[tid + s]; __syncthreads(); }
        if (tid == 0) c0out[i] = red[0] + wq_b[0];
    } else if (b < 13827) {
        int v = b - 13059;
        int o = v & 255, jb = v >> 8;
        float* wrow = smf;         // 256
        float* red = smf + 256;    // 256
        wrow[tid] = W_fus[o * 256 + tid];
        __syncthreads();
        int j = jb * 256 + tid;
        float acc = 0.f;
        #pragma unroll 8
        for (int c = 0; c < 256; ++c) acc = fmaf(wrow[c], W_res[(size_t)c * 768 + j], acc);
        Wcat[o * 1024 + 256 + j] = f2bf(acc);
        if (jb == 0) {
            Wcat[o * 1024 + tid] = f2bf(wrow[tid]);
            red[tid] = wrow[tid] * b_res[tid];
            __syncthreads();
            for (int s = 128; s > 0; s >>= 1) { if (tid < s) red[tid] += red[tid + s]; __syncthreads(); }
            if (tid == 0) biasc[o] = red[0] + b_fus[o];
        }
    } else if (b < 13875) {
        int i = (b - 13827) * 256 + tid;   // < 12288 (xq ++ posq)
        zeroreg[i] = 0.f;
    } else if (b < 14643) {                // W_expT[c][r] = W_exp[r][c]  (768x256)
        int idx = (b - 13875) * 256 + tid;
        W_expT[(idx & 255) * 768 + (idx >> 8)] = W_exp[idx];
    } else if (b < 14771) {                // swqT[c][q] (128x256 src)
        int idx = (b - 14643) * 256 + tid;
        swqT[(idx & 255) * 128 + (idx >> 8)] = sp_wq_w[idx];
    } else if (b < 14899) {                // chvT[c][q] (128x256 src)
        int idx = (b - 14771) * 256 + tid;
        chvT[(idx & 255) * 128 + (idx >> 8)] = ch_wv_w[idx];
    } else {                               // chzT[c2][o] (256x128 src)
        int idx = (b - 14899) * 256 + tid;
        chzT[(idx & 127) * 256 + (idx >> 7)] = ch_wz_w[idx];
    }
}

// ---- blocks 0..511: qdot (512 thr, 64 p each, 8-way k-split) + single-wave
//      softmax partials. blocks 512..535: ubar (finalizes xbar/posbar).
__global__ __launch_bounds__(512) void qdot_ubar(
    const float* __restrict__ x, const float* __restrict__ pos,
    const float* __restrict__ g, const float* __restrict__ c0in,
    const float* __restrict__ wq, float* __restrict__ qdot,
    const float* __restrict__ b_exp,
    const float* __restrict__ xpa, const float* __restrict__ xp6,
    const float* __restrict__ ppa, const float* __restrict__ pp6,
    const float* __restrict__ W_expT, float* __restrict__ ubar,
    float* __restrict__ qpm, float* __restrict__ qpz)
{
    int blk = blockIdx.x, tid = threadIdx.x;
    if (blk < 512) {
        int n = blk >> 6;
        int ph = tid & 63, cq = tid >> 6;          // 8 c-groups of 32
        int pb = blk & 63;
        int p = pb * 64 + ph;
        __shared__ float gl[768];
        __shared__ float wql[256];
        __shared__ float4 red4[512];
        for (int k = tid; k < 768; k += 512) gl[k] = g[k];
        if (tid < 256) wql[tid] = wq[tid];
        __syncthreads();
        const float* xp = x + (((size_t)n) << 20) + p;
        const float* pp = pos + p;
        float q0 = 0.f, q1 = 0.f, q2 = 0.f, qp = 0.f;
        #pragma unroll 4
        for (int c = cq * 32; c < cq * 32 + 32; ++c) {
            float xv = xp[(size_t)c << 12];
            float pv = pp[(size_t)c << 12];
            q0 = fmaf(gl[c], xv, q0);
            q1 = fmaf(gl[256 + c], xv, q1);
            q2 = fmaf(gl[512 + c], xv, q2);
            qp = fmaf(wql[c], pv, qp);
        }
        red4[tid] = make_float4(q0, q1, q2, qp);
        __syncthreads();
        if (tid < 64) {
            float sx = 0.f, sy = 0.f, sz = 0.f, sw = 0.f;
            #pragma unroll
            for (int k = 0; k < 8; ++k) {
                float4 t4 = red4[k * 64 + tid];
                sx += t4.x; sy += t4.y; sz += t4.z; sw += t4.w;
            }
            float va = sx + sw + c0in[0];
            float vb = sy + sw + c0in[1];
            float vc = sz + sw + c0in[2];
            qdot[((0 * 8 + n) << 12) + p] = va;
            qdot[((1 * 8 + n) << 12) + p] = vb;
            qdot[((2 * 8 + n) << 12) + p] = vc;
            // single-wave softmax partials over the 64 p's
            float vv[3] = {va, vb, vc};
            int y = p >> 6, xx = p & 63;
            #pragma unroll
            for (int i = 0; i < 3; ++i) {
                int win = 2 * (i + 1), sh = 64 / win, kh = sh + 64 % win;
                float cf = (float)(cnt1f(y, sh, kh, win) * cnt1f(xx, sh, kh, win));
                float m = vv[i];
                #pragma unroll
                for (int d2 = 32; d2; d2 >>= 1) m = fmaxf(m, __shfl_down(m, d2, 64));
                m = __shfl(m, 0, 64);
                float z = cf * expf(vv[i] - m);
                #pragma unroll
                for (int d2 = 32; d2; d2 >>= 1) z += __shfl_down(z, d2, 64);
                if (tid == 0) {
                    int bidx = (i * 8 + n) * 64 + pb;
                    qpm[bidx] = m; qpz[bidx] = z;
                }
            }
        }
    } else {
        int v = blk - 512;
        int i = v >> 3, n = v & 7;
        __shared__ float xbl[256];
        if (tid < 256) {
            const float* xp_ = (i < 2) ? xpa : xp6;
            float s = 0.f;
            #pragma unroll 8
            for (int k = 0; k < 128; ++k) s += xp_[k * 2048 + n * 256 + tid];
            xbl[tid] = s;
        }
        __syncthreads();
        if (tid < 256) {
            const float* pp_ = (i < 2) ? ppa : pp6;
            float pb = 0.f;
            #pragma unroll
            for (int k = 0; k < 16; ++k) pb += pp_[k * 256 + tid];
            int win = 2 * (i + 1), sh = 64 / win, kh = sh + 64 % win;
            float Li = (float)(win * win * kh * kh);
            float acc = b_exp[i * 256 + tid] * Li + pb;
            const float* Wc = W_expT + i * 256 + tid;
            #pragma unroll 8
            for (int j = 0; j < 256; ++j) acc = fmaf(Wc[(size_t)j * 768], xbl[j], acc);
            ubar[(i * 8 + n) * 256 + tid] = acc;
        }
    }
}

// ---- merge softmax partials, spq, w_eff, h, btot (grid 3 x 8, 1024 thr,
//      4-8 way k-split on each matvec — was 24 blocks x 4 waves, latency-bound)
__global__ __launch_bounds__(1024) void pass_b_h(
    const float* __restrict__ ubar_raw,
    const float* __restrict__ swqT, const float* __restrict__ sp_wq_b,
    const float* __restrict__ sp_wv_w, const float* __restrict__ sp_wv_b,
    const float* __restrict__ W_exp, const float* __restrict__ b_exp,
    const float* __restrict__ qpm, const float* __restrict__ qpz,
    float* __restrict__ Mn, float* __restrict__ invZn,
    float* __restrict__ w_eff, float* __restrict__ h, float* __restrict__ btot)
{
    int i = blockIdx.x, n = blockIdx.y, tid = threadIdx.x;
    int b = i * 8 + n;
    int win = 2 * (i + 1), sh = 64 / win, kh = sh + 64 % win;
    float invL = 1.f / (float)(win * win * kh * kh);
    __shared__ float ub[256];
    __shared__ float spq[128];
    __shared__ float we[256];
    __shared__ float ps[1024];
    __shared__ float red[256];
    // merge the 64 per-block (m,z) partials (wave 0 only)
    if (tid < 64) {
        float mp = qpm[b * 64 + tid];
        float zp = qpz[b * 64 + tid];
        float mm = mp;
        #pragma unroll
        for (int d = 32; d; d >>= 1) mm = fmaxf(mm, __shfl_down(mm, d, 64));
        float M = __shfl(mm, 0, 64);
        float zz = zp * expf(mp - M);
        #pragma unroll
        for (int d = 32; d; d >>= 1) zz += __shfl_down(zz, d, 64);
        if (tid == 0) { Mn[b] = M; invZn[b] = 1.f / zz; }
    }
    if (tid < 256) ub[tid] = ubar_raw[b * 256 + tid] * invL;
    __syncthreads();
    // swq matvec: 128 outputs, 8 segs x 32 c
    {
        int q = tid & 127, s8 = tid >> 7;
        float a = 0.f;
        #pragma unroll 8
        for (int c = s8 * 32; c < s8 * 32 + 32; ++c) a = fmaf(swqT[c * 128 + q], ub[c], a);
        ps[tid] = a;
    }
    __syncthreads();
    float sl = 0.f;
    if (tid < 128) {
        float a = sp_wq_b[tid];
        #pragma unroll
        for (int k = 0; k < 8; ++k) a += ps[k * 128 + tid];
        sl = a;
        red[tid] = a;
    }
    __syncthreads();
    for (int s = 64; s > 0; s >>= 1) { if (tid < s) red[tid] = fmaxf(red[tid], red[tid + s]); __syncthreads(); }
    float m2 = red[0]; __syncthreads();
    float e = (tid < 128) ? expf(sl - m2) : 0.f;
    if (tid < 128) red[tid] = e;
    __syncthreads();
    for (int s = 64; s > 0; s >>= 1) { if (tid < s) red[tid] += red[tid + s]; __syncthreads(); }
    float S2 = red[0]; __syncthreads();
    if (tid < 128) spq[tid] = e / S2;
    __syncthreads();
    // weff matvec: 256 outputs, 4 segs x 32 q
    {
        int c = tid & 255, s4 = tid >> 8;
        float a = 0.f;
        #pragma unroll 8
        for (int q = s4 * 32; q < s4 * 32 + 32; ++q) a = fmaf(spq[q], sp_wv_w[q * 256 + c], a);
        ps[tid] = a;
    }
    __syncthreads();
    if (tid < 256) {
        float a = ps[tid] + ps[256 + tid] + ps[512 + tid] + ps[768 + tid];
        w_eff[b * 256 + tid] = a;
        we[tid] = a;
    }
    __syncthreads();
    // h matvec: 256 outputs, 4 segs x 64 oc
    {
        int c = tid & 255, s4 = tid >> 8;
        const float* Wb2 = W_exp + (size_t)i * 65536 + c;
        float a = 0.f;
        #pragma unroll 8
        for (int oc = s4 * 64; oc < s4 * 64 + 64; ++oc) a = fmaf(we[oc], Wb2[(size_t)oc * 256], a);
        ps[tid] = a;
    }
    __syncthreads();
    if (tid < 256) {
        h[b * 256 + tid] = ps[tid] + ps[256 + tid] + ps[512 + tid] + ps[768 + tid];
        red[tid] = we[tid] * b_exp[i * 256 + tid] + ((tid < 128) ? spq[tid] * sp_wv_b[tid] : 0.f);
    }
    __syncthreads();
    for (int s = 128; s > 0; s >>= 1) { if (tid < s) red[tid] += red[tid + s]; __syncthreads(); }
    if (tid == 0) btot[b] = red[0];
}

// --- phase1: spw = sigmoid(h.x + weff.pos + btot), t = cnt*softmax(qdot)
// --- phase2: xq[c]  += sum_p t*xbT[p][c]  (bf16), posq[c] += sum_p t*posT[p][c]
// 64 p per block (2x grid vs round 2 for occupancy).
__global__ __launch_bounds__(512) void spw_t_xq(
    const float* __restrict__ x, const float* __restrict__ pos,
    const float* __restrict__ h, const float* __restrict__ weff,
    const float* __restrict__ qdot, const float* __restrict__ Mn,
    const float* __restrict__ invZn, const float* __restrict__ btot,
    const ushort_t* __restrict__ xbT, const float* __restrict__ posT,
    float* __restrict__ spw, float* __restrict__ xq, float* __restrict__ posq)
{
    int n = blockIdx.y, tid = threadIdx.x;
    int ph = tid & 63, cq = tid >> 6;              // 8 c-groups of 32
    int p0b = blockIdx.x * 64;
    int p = p0b + ph;
    __shared__ float hl[768], wl[768];
    __shared__ float4 red4[512];
    __shared__ float tl[3][64];
    for (int k = tid; k < 768; k += 512) {
        int i = k >> 8, c = k & 255;
        hl[k] = h[(i * 8 + n) * 256 + c];
        wl[k] = weff[(i * 8 + n) * 256 + c];
    }
    __syncthreads();
    const float* xp = x + (((size_t)n) << 20) + p;
    const float* pp = pos + p;
    float a0 = 0.f, a1 = 0.f, a2 = 0.f;
    #pragma unroll 4
    for (int c = cq * 32; c < cq * 32 + 32; ++c) {
        float xv = xp[(size_t)c << 12];
        float pv = pp[(size_t)c << 12];
        a0 += hl[c] * xv + wl[c] * pv;
        a1 += hl[256 + c] * xv + wl[256 + c] * pv;
        a2 += hl[512 + c] * xv + wl[512 + c] * pv;
    }
    red4[tid] = make_float4(a0, a1, a2, 0.f);
    __syncthreads();
    if (tid < 64) {
        float sx = 0.f, sy = 0.f, sz = 0.f;
        #pragma unroll
        for (int k = 0; k < 8; ++k) {
            float4 t4 = red4[k * 64 + tid];
            sx += t4.x; sy += t4.y; sz += t4.z;
        }
        float av[3] = {sx, sy, sz};
        int y = p >> 6, xx = p & 63;
        #pragma unroll
        for (int i = 0; i < 3; ++i) {
            int b = i * 8 + n;
            int win = 2 * (i + 1), sh = 64 / win, kh = sh + 64 % win;
            float cf = (float)(cnt1f(y, sh, kh, win) * cnt1f(xx, sh, kh, win));
            int idx = (b << 12) + p;
            spw[idx] = 1.f / (1.f + expf(-(av[i] + btot[b])));
            tl[i][ph] = cf * expf(qdot[idx] - Mn[b]) * invZn[b];
        }
    }
    __syncthreads();
    // phase 2
    int c = tid & 255;
    int half = tid >> 8;
    float s0 = 0.f, s1 = 0.f, s2 = 0.f;
    if (half == 0) {
        const ushort_t* xb = xbT + (((size_t)((n << 12) + p0b)) << 8) + c;
        #pragma unroll 4
        for (int pl = 0; pl < 64; ++pl) {
            float xv = bf2f(xb[(size_t)pl << 8]);
            s0 = fmaf(tl[0][pl], xv, s0);
            s1 = fmaf(tl[1][pl], xv, s1);
            s2 = fmaf(tl[2][pl], xv, s2);
        }
        atomicAdd(&xq[(0 * 8 + n) * 256 + c], s0);
        atomicAdd(&xq[(1 * 8 + n) * 256 + c], s1);
        atomicAdd(&xq[(2 * 8 + n) * 256 + c], s2);
    } else {
        const float* pt = posT + (((size_t)p0b) << 8) + c;
        #pragma unroll 4
        for (int pl = 0; pl < 64; ++pl) {
            float pv = pt[(size_t)pl << 8];
            s0 = fmaf(tl[0][pl], pv, s0);
            s1 = fmaf(tl[1][pl], pv, s1);
            s2 = fmaf(tl[2][pl], pv, s2);
        }
        atomicAdd(&posq[(0 * 8 + n) * 256 + c], s0);
        atomicAdd(&posq[(1 * 8 + n) * 256 + c], s1);
        atomicAdd(&posq[(2 * 8 + n) * 256 + c], s2);
    }
}

// ---- uq = W_exp_i@xq + b + posq; z->wz->LN->sigmoid->chw (grid 3x8, 1024 thr)
__global__ __launch_bounds__(1024) void pass_d_uq(
    const float* __restrict__ W_expT, const float* __restrict__ b_exp,
    const float* __restrict__ xq, const float* __restrict__ posq,
    const float* __restrict__ chvT, const float* __restrict__ ch_wv_b,
    const float* __restrict__ chzT, const float* __restrict__ ch_wz_b,
    const float* __restrict__ ln_g, const float* __restrict__ ln_b,
    float* __restrict__ ch_w)
{
    int i = blockIdx.x, n = blockIdx.y, tid = threadIdx.x;
    int b = i * 8 + n;
    __shared__ float xql[256];
    __shared__ float uql[256];
    __shared__ float zz[128];
    __shared__ float ps[1024];
    __shared__ float red[256];
    if (tid < 256) xql[tid] = xq[b * 256 + tid];
    __syncthreads();
    // uq matvec: 256 outputs, 4 segs x 64 cin
    {
        int oc = tid & 255, s4 = tid >> 8;
        const float* Wc = W_expT + i * 256 + oc;
        float a = 0.f;
        #pragma unroll 8
        for (int cin = s4 * 64; cin < s4 * 64 + 64; ++cin) a = fmaf(Wc[(size_t)cin * 768], xql[cin], a);
        ps[tid] = a;
    }
    __syncthreads();
    if (tid < 256)
        uql[tid] = b_exp[i * 256 + tid] + posq[b * 256 + tid]
                 + ps[tid] + ps[256 + tid] + ps[512 + tid] + ps[768 + tid];
    __syncthreads();
    // zz matvec: 128 outputs, 8 segs x 32 c
    {
        int q = tid & 127, s8 = tid >> 7;
        float a = 0.f;
        #pragma unroll 8
        for (int c = s8 * 32; c < s8 * 32 + 32; ++c) a = fmaf(chvT[c * 128 + q], uql[c], a);
        ps[tid] = a;
    }
    __syncthreads();
    if (tid < 128) {
        float a = ch_wv_b[tid];
        #pragma unroll
        for (int k = 0; k < 8; ++k) a += ps[k * 128 + tid];
        zz[tid] = a;
    }
    __syncthreads();
    // wz matvec: 256 outputs, 4 segs x 32 c2
    {
        int o = tid & 255, s4 = tid >> 8;
        float a = 0.f;
        #pragma unroll 8
        for (int c2 = s4 * 32; c2 < s4 * 32 + 32; ++c2) a = fmaf(chzT[c2 * 256 + o], zz[c2], a);
        ps[tid] = a;
    }
    __syncthreads();
    float wz = 0.f;
    if (tid < 256) {
        wz = ch_wz_b[tid] + ps[tid] + ps[256 + tid] + ps[512 + tid] + ps[768 + tid];
        red[tid] = wz;
    }
    __syncthreads();
    for (int s = 128; s > 0; s >>= 1) { if (tid < s) red[tid] += red[tid + s]; __syncthreads(); }
    float mean = red[0] * (1.f / 256.f); __syncthreads();
    float d = wz - mean;
    if (tid < 256) red[tid] = d * d;
    __syncthreads();
    for (int s = 128; s > 0; s >>= 1) { if (tid < s) red[tid] += red[tid + s]; __syncthreads(); }
    float var = red[0] * (1.f / 256.f);
    if (tid < 256) {
        float xn = d / sqrtf(var + 1e-5f);
        ch_w[b * 256 + tid] = 1.f / (1.f + expf(-(xn * ln_g[tid] + ln_b[tid])));
    }
}

// ---- MFMA GEMM 1 (LDS-staged gated epilogue): exT bf16 [n][p][768]
//   e = W_exp@x+b;  combined = e + (e + posT)*(chw + spw)
__global__ __launch_bounds__(256) void gemm_expT(
    const ushort_t* __restrict__ Wb, const ushort_t* __restrict__ XT,
    const float* __restrict__ bias, const float* __restrict__ posT,
    const float* __restrict__ chw, const float* __restrict__ spw,
    ushort_t* __restrict__ OutT)
{
    __shared__ ushort_t SM[10240];           // As | Bs ; reused as stage [128][72]
    ushort_t* As = SM;
    ushort_t* Bs = SM + 5120;
    int n = blockIdx.z;
    int p0 = blockIdx.x * 128;
    int o0 = blockIdx.y * 128;
    int t = threadIdx.x;
    int lane = t & 63, wave = t >> 6;
    int wm = (wave & 1) * 64, wn = (wave >> 1) * 64;
    int lr = lane & 15, lk = (lane >> 4) * 8;
    int ar = t >> 2, ac = (t & 3) * 8;
    const ushort_t* A0 = Wb + (size_t)(o0 + ar) * 256 + ac;
    const ushort_t* A1 = Wb + (size_t)(o0 + ar + 64) * 256 + ac;
    const ushort_t* B0 = XT + (((size_t)(n << 12)) + p0 + ar) * 256 + ac;
    const ushort_t* B1 = XT + (((size_t)(n << 12)) + p0 + ar + 64) * 256 + ac;
    floatx4 acc[4][4] = {};
    for (int k0 = 0; k0 < 256; k0 += 32) {
        uint4 a0 = *(const uint4*)(A0 + k0);
        uint4 a1 = *(const uint4*)(A1 + k0);
        uint4 b0 = *(const uint4*)(B0 + k0);
        uint4 b1 = *(const uint4*)(B1 + k0);
        __syncthreads();
        *(uint4*)&As[ar * 40 + ac] = a0;
        *(uint4*)&As[(ar + 64) * 40 + ac] = a1;
        *(uint4*)&Bs[ar * 40 + ac] = b0;
        *(uint4*)&Bs[(ar + 64) * 40 + ac] = b1;
        __syncthreads();
        bf16x8 af[4], bfr[4];
        #pragma unroll
        for (int mi = 0; mi < 4; ++mi)
            af[mi] = *(const bf16x8*)&As[(wm + mi * 16 + lr) * 40 + lk];
        #pragma unroll
        for (int ni = 0; ni < 4; ++ni)
            bfr[ni] = *(const bf16x8*)&Bs[(wn + ni * 16 + lr) * 40 + lk];
        #pragma unroll
        for (int mi = 0; mi < 4; ++mi)
            #pragma unroll
            for (int ni = 0; ni < 4; ++ni)
                acc[mi][ni] = __builtin_amdgcn_mfma_f32_16x16x32_bf16(
                    af[mi], bfr[ni], acc[mi][ni], 0, 0, 0);
    }
    int col = lane & 15, rb = (lane >> 4) * 4;
    int ibr = o0 >> 8;
    int bi = ibr * 8 + n;
    #pragma unroll
    for (int r = 0; r < 2; ++r) {
        __syncthreads();
        if (wm == r * 64) {
            #pragma unroll
            for (int mi = 0; mi < 4; ++mi) {
                int o_loc = mi * 16 + rb;
                float4 bo = *(const float4*)&bias[o0 + r * 64 + o_loc];
                #pragma unroll
                for (int ni = 0; ni < 4; ++ni) {
                    int prow = wn + ni * 16 + col;
                    floatx4 v = acc[mi][ni];
                    unsigned lo = (unsigned)f2bf(v[0] + bo.x) | ((unsigned)f2bf(v[1] + bo.y) << 16);
                    unsigned hi = (unsigned)f2bf(v[2] + bo.z) | ((unsigned)f2bf(v[3] + bo.w) << 16);
                    *(uint2*)&SM[prow * 72 + o_loc] = make_uint2(lo, hi);
                }
            }
        }
        __syncthreads();
        #pragma unroll
        for (int it = 0; it < 4; ++it) {
            int slot = it * 256 + t;
            int pl = slot >> 3, j = (slot & 7) * 8;
            uint4 raw = *(const uint4*)&SM[pl * 72 + j];
            float e0 = bf2f((ushort_t)(raw.x & 0xFFFF)), e1 = bf2f((ushort_t)(raw.x >> 16));
            float e2 = bf2f((ushort_t)(raw.y & 0xFFFF)), e3 = bf2f((ushort_t)(raw.y >> 16));
            float e4 = bf2f((ushort_t)(raw.z & 0xFFFF)), e5 = bf2f((ushort_t)(raw.z >> 16));
            float e6 = bf2f((ushort_t)(raw.w & 0xFFFF)), e7 = bf2f((ushort_t)(raw.w >> 16));
            int p = p0 + pl;
            int cbase = (o0 & 255) + r * 64 + j;
            float s = spw[(bi << 12) + p];
            float4 q0 = *(const float4*)&posT[p * 256 + cbase];
            float4 q1 = *(const float4*)&posT[p * 256 + cbase + 4];
            float4 w0 = *(const float4*)&chw[bi * 256 + cbase];
            float4 w1 = *(const float4*)&chw[bi * 256 + cbase + 4];
            float r0 = e0 + (e0 + q0.x) * (w0.x + s);
            float r1 = e1 + (e1 + q0.y) * (w0.y + s);
            float r2 = e2 + (e2 + q0.z) * (w0.z + s);
            float r3 = e3 + (e3 + q0.w) * (w0.w + s);
            float r4 = e4 + (e4 + q1.x) * (w1.x + s);
            float r5 = e5 + (e5 + q1.y) * (w1.y + s);
            float r6 = e6 + (e6 + q1.z) * (w1.z + s);
            float r7 = e7 + (e7 + q1.w) * (w1.w + s);
            uint4 outv;
            outv.x = (unsigned)f2bf(r0) | ((unsigned)f2bf(r1) << 16);
            outv.y = (unsigned)f2bf(r2) | ((unsigned)f2bf(r3) << 16);
            outv.z = (unsigned)f2bf(r4) | ((unsigned)f2bf(r5) << 16);
            outv.w = (unsigned)f2bf(r6) | ((unsigned)f2bf(r7) << 16);
            *(uint4*)&OutT[(((size_t)(n << 12)) + p) * 768 + o0 + r * 64 + j] = outv;
        }
    }
}

// ---- MFMA GEMM 2: out = Wcat @ [x ; combined] + biasc, fp32 [n][256][4096]
__global__ __launch_bounds__(256) void gemm_out(
    const ushort_t* __restrict__ Wcat, const ushort_t* __restrict__ XT,
    const ushort_t* __restrict__ CT, const float* __restrict__ biasc,
    float* __restrict__ Out)
{
    __shared__ ushort_t As[128 * 40];
    __shared__ ushort_t Bs[128 * 40];
    int n = blockIdx.z;
    int p0 = blockIdx.x * 128;
    int o0 = blockIdx.y * 128;
    int t = threadIdx.x;
    int lane = t & 63, wave = t >> 6;
    int wm = (wave & 1) * 64, wn = (wave >> 1) * 64;
    int lr = lane & 15, lk = (lane >> 4) * 8;
    int ar = t >> 2, ac = (t & 3) * 8;
    const ushort_t* A0 = Wcat + (size_t)(o0 + ar) * 1024 + ac;
    const ushort_t* A1 = Wcat + (size_t)(o0 + ar + 64) * 1024 + ac;
    const ushort_t* BX0 = XT + (((size_t)(n << 12)) + p0 + ar) * 256 + ac;
    const ushort_t* BX1 = XT + (((size_t)(n << 12)) + p0 + ar + 64) * 256 + ac;
    const ushort_t* BC0 = CT + (((size_t)(n << 12)) + p0 + ar) * 768 + ac;
    const ushort_t* BC1 = CT + (((size_t)(n << 12)) + p0 + ar + 64) * 768 + ac;
    floatx4 acc[4][4] = {};
    for (int k0 = 0; k0 < 1024; k0 += 32) {
        const ushort_t* pb0 = (k0 < 256) ? (BX0 + k0) : (BC0 + (k0 - 256));
        const ushort_t* pb1 = (k0 < 256) ? (BX1 + k0) : (BC1 + (k0 - 256));
        uint4 a0 = *(const uint4*)(A0 + k0);
        uint4 a1 = *(const uint4*)(A1 + k0);
        uint4 b0 = *(const uint4*)pb0;
        uint4 b1 = *(const uint4*)pb1;
        __syncthreads();
        *(uint4*)&As[ar * 40 + ac] = a0;
        *(uint4*)&As[(ar + 64) * 40 + ac] = a1;
        *(uint4*)&Bs[ar * 40 + ac] = b0;
        *(uint4*)&Bs[(ar + 64) * 40 + ac] = b1;
        __syncthreads();
        bf16x8 af[4], bfr[4];
        #pragma unroll
        for (int mi = 0; mi < 4; ++mi)
            af[mi] = *(const bf16x8*)&As[(wm + mi * 16 + lr) * 40 + lk];
        #pragma unroll
        for (int ni = 0; ni < 4; ++ni)
            bfr[ni] = *(const bf16x8*)&Bs[(wn + ni * 16 + lr) * 40 + lk];
        #pragma unroll
        for (int mi = 0; mi < 4; ++mi)
            #pragma unroll
            for (int ni = 0; ni < 4; ++ni)
                acc[mi][ni] = __builtin_amdgcn_mfma_f32_16x16x32_bf16(
                    af[mi], bfr[ni], acc[mi][ni], 0, 0, 0);
    }
    int col = lane & 15, rb = (lane >> 4) * 4;
    #pragma unroll
    for (int mi = 0; mi < 4; ++mi) {
        int o = o0 + wm + mi * 16 + rb;
        float4 bo = *(const float4*)&biasc[o];
        #pragma unroll
        for (int r = 0; r < 4; ++r) {
            float br = (r == 0) ? bo.x : (r == 1) ? bo.y : (r == 2) ? bo.z : bo.w;
            #pragma unroll
            for (int ni = 0; ni < 4; ++ni) {
                int p = p0 + wn + ni * 16 + col;
                Out[(((size_t)(n * 256 + o + r)) << 12) + p] = acc[mi][ni][r] + br;
            }
        }
    }
}

// ---------------------------------------------------------------------------
extern "C" void kernel_launch(void* const* d_in, const int* in_sizes, int n_in,
                              void* d_out, int out_size, void* d_ws, size_t ws_size,
                              hipStream_t stream) {
    const float* x        = (const float*)d_in[0];
    const float* w_exp    = (const float*)d_in[1];
    const float* b_exp    = (const float*)d_in[2];
    const float* w_res    = (const float*)d_in[3];
    const float* b_res    = (const float*)d_in[4];
    const float* w_fus    = (const float*)d_in[5];
    const float* b_fus    = (const float*)d_in[6];
    const float* ch_wv_w  = (const float*)d_in[7];
    const float* ch_wv_b  = (const float*)d_in[8];
    const float* ch_wq_w  = (const float*)d_in[9];
    const float* ch_wq_b  = (const float*)d_in[10];
    const float* ch_wz_w  = (const float*)d_in[11];
    const float* ch_wz_b  = (const float*)d_in[12];
    const float* ln_g     = (const float*)d_in[13];
    const float* ln_b     = (const float*)d_in[14];
    const float* sp_wv_w  = (const float*)d_in[15];
    const float* sp_wv_b  = (const float*)d_in[16];
    const float* sp_wq_w  = (const float*)d_in[17];
    const float* sp_wq_b  = (const float*)d_in[18];
    float* out = (float*)d_out;
    float* ws  = (float*)d_ws;

    // workspace layout (float offsets)
    float*    pos   = ws + 0;                      // 1,048,576
    float*    posT  = ws + 1048576;                // 1,048,576
    ushort_t* xbT   = (ushort_t*)(ws + 2097152);   // 8,388,608 ushorts
    ushort_t* exT   = (ushort_t*)(ws + 6291456);   // 25,165,824 ushorts
    ushort_t* wexpb = (ushort_t*)(ws + 18874368);  // 196,608 ushorts
    ushort_t* Wcat  = (ushort_t*)(ws + 18972672);  // 262,144 ushorts
    float*    qdot  = ws + 19103744;   // 98,304
    float*    spw   = ws + 19300352;   // 98,304
    float*    g     = ws + 19398656;   // 768
    float*    c0v   = ws + 19399424;   // 4
    float*    ubar  = ws + 19399428;   // 6,144
    float*    Mn    = ws + 19410180;   // 24
    float*    iZ    = ws + 19410204;   // 24
    float*    weff  = ws + 19410228;   // 6,144
    float*    btot  = ws + 19416372;   // 24
    float*    hb    = ws + 19416396;   // 6,144
    float*    xq    = ws + 19422540;   // 6,144  (zeroed in prep_all)
    float*    posq  = ws + 19428684;   // 6,144  (zeroed in prep_all)
    float*    chw   = ws + 19434828;   // 6,144
    float*    biasc = ws + 19440972;   // 256
    float*    W_expT = ws + 19441228;  // 196,608
    float*    swqT   = ws + 19637836;  // 32,768
    float*    chvT   = ws + 19670604;  // 32,768
    float*    chzT   = ws + 19703372;  // 32,768
    float*    xpa    = ws + 19736140;  // 262,144 (128 pblk x [n*256+c])
    float*    xp6    = ws + 19998284;  // 262,144
    float*    ppa    = ws + 20260428;  // 4,096 (16 slots x 256 c)
    float*    pp6    = ws + 20264524;  // 4,096
    float*    qpm    = ws + 20268620;  // 1,536 (3*8*64 softmax partial max)
    float*    qpz    = ws + 20270156;  // 1,536 (partial expsum)

    prep_all<<<15027, 256, 0, stream>>>(x, w_exp, b_exp, ch_wq_w, ch_wq_b,
                                        w_fus, w_res, b_res, b_fus,
                                        sp_wq_w, ch_wv_w, ch_wz_w,
                                        pos, posT, xbT, wexpb, g, c0v,
                                        Wcat, biasc, xq,
                                        W_expT, swqT, chvT, chzT,
                                        xpa, xp6, ppa, pp6);
    qdot_ubar<<<536, 512, 0, stream>>>(x, pos, g, c0v, ch_wq_w, qdot,
                                       b_exp, xpa, xp6, ppa, pp6, W_expT, ubar,
                                       qpm, qpz);
    pass_b_h<<<dim3(3, 8), 1024, 0, stream>>>(ubar, swqT, sp_wq_b,
                                              sp_wv_w, sp_wv_b, w_exp, b_exp,
                                              qpm, qpz,
                                              Mn, iZ, weff, hb, btot);
    spw_t_xq<<<dim3(64, 8), 512, 0, stream>>>(x, pos, hb, weff, qdot, Mn, iZ,
                                              btot, xbT, posT, spw, xq, posq);
    pass_d_uq<<<dim3(3, 8), 1024, 0, stream>>>(W_expT, b_exp, xq, posq,
                                               chvT, ch_wv_b, chzT, ch_wz_b,
                                               ln_g, ln_b, chw);
    gemm_expT<<<dim3(32, 6, 8), 256, 0, stream>>>(wexpb, xbT, b_exp, posT, chw, spw, exT);
    gemm_out<<<dim3(32, 2, 8), 256, 0, stream>>>(Wcat, xbT, exT, biasc, out);
}

// Round 9
// 258.207 us; speedup vs baseline: 1.2517x; 1.0013x over previous
//
#include <hip/hip_runtime.h>
#include <cstddef>
#include <cstdint>

// ---------------------------------------------------------------------------
// PatchAttention, algebraically simplified + bf16 MFMA GEMMs.
// 7 dispatches: prep_all (+xbar partials, +weight transposes) -> qdot+ubar
//               (+softmax partials) -> pass_b_h -> spw_t(+xq) -> pass_d_uq
//               -> gemm_expT (gated epilogue) -> gemm_out
// GEMMs: round-0 reg-staged 128x128 (measured best; 3 rewrites regressed).
// Round 8: pass_b_h/pass_d_uq widened to 1024 thr (258.5us, best).
// Round 9: qdot/spw x-scans float4-vectorized along p (thread owns 4 p) —
// was 1 scalar load per (c,p): 64 VMEM instr/thread at 256B/wave-instr.
// ---------------------------------------------------------------------------

#define HW 4096
typedef unsigned short ushort_t;
typedef __attribute__((ext_vector_type(8))) short bf16x8;
typedef __attribute__((ext_vector_type(4))) float floatx4;

#define FMA4(acc, s, v) { acc.x = fmaf((s), (v).x, acc.x); acc.y = fmaf((s), (v).y, acc.y); \
                          acc.z = fmaf((s), (v).z, acc.z); acc.w = fmaf((s), (v).w, acc.w); }
#define SHRED4(v) { v.x += __shfl_down(v.x, 16, 64); v.y += __shfl_down(v.y, 16, 64); \
                    v.z += __shfl_down(v.z, 16, 64); v.w += __shfl_down(v.w, 16, 64); \
                    v.x += __shfl_down(v.x, 32, 64); v.y += __shfl_down(v.y, 32, 64); \
                    v.z += __shfl_down(v.z, 32, 64); v.w += __shfl_down(v.w, 32, 64); }
#define ADD4(a, b) { a.x += (b).x; a.y += (b).y; a.z += (b).z; a.w += (b).w; }

__device__ __forceinline__ ushort_t f2bf(float f) {
    unsigned u = __float_as_uint(f);
    u += 0x7FFF + ((u >> 16) & 1);           // RNE
    return (ushort_t)(u >> 16);
}
__device__ __forceinline__ float bf2f(ushort_t h) {
    return __uint_as_float(((unsigned)h) << 16);
}

__device__ __forceinline__ int cnt1f(int y, int sh, int kh, int win) {
    int t = y - kh + sh;
    int lo = t > 0 ? t / sh : 0;
    int hi = min(win - 1, y / sh);
    return hi - lo + 1;
}

__device__ __forceinline__ float posval(int f) {
    int row = f >> 8, col = f & 255;
    int a = row >> 6, b = row & 63;
    int g = col >> 6, k = col & 63;
    float omega = expf(-(float)k * (9.2103403719761836f / 64.f)); // 10000^(-k/64)
    float arg = (g < 2 ? (float)a : (float)b) * omega;
    return (g & 1) ? cosf(arg) : sinf(arg);
}

// ---------------- prep_all: pos/posT (+posbar partials), trans_x (+xbar
// partials), conv_bf16, prep_g, prep_wcomb, zero xq/posq, weight transposes.
// 15,027 blocks x 256 threads.
__global__ __launch_bounds__(256) void prep_all(
    const float* __restrict__ x, const float* __restrict__ W_exp,
    const float* __restrict__ b_exp, const float* __restrict__ wq,
    const float* __restrict__ wq_b, const float* __restrict__ W_fus,
    const float* __restrict__ W_res, const float* __restrict__ b_res,
    const float* __restrict__ b_fus, const float* __restrict__ sp_wq_w,
    const float* __restrict__ ch_wv_w, const float* __restrict__ ch_wz_w,
    float* __restrict__ pos, float* __restrict__ posT,
    ushort_t* __restrict__ xbT, ushort_t* __restrict__ wexpb,
    float* __restrict__ g, float* __restrict__ c0out,
    ushort_t* __restrict__ Wcat, float* __restrict__ biasc,
    float* __restrict__ zeroreg,
    float* __restrict__ W_expT, float* __restrict__ swqT,
    float* __restrict__ chvT, float* __restrict__ chzT,
    float* __restrict__ xpa, float* __restrict__ xp6,
    float* __restrict__ ppa, float* __restrict__ pp6)
{
    __shared__ float smf[1184];
    __shared__ float wred[8];
    int b = blockIdx.x, tid = threadIdx.x;
    if (b < 4096) {
        int idx = b * 256 + tid;
        float pv = posval(idx);
        pos[idx] = pv;
        int p2 = idx >> 8, c2 = idx & 255;
        posT[idx] = posval(c2 * 4096 + p2);
        // posbar partials: idx = c*4096 + p -> c = b>>4, p = (b&15)*256+tid
        int p = ((b & 15) << 8) + tid;
        int y = p >> 6, xx = p & 63;
        float cf = (float)(cnt1f(y, 10, 14, 6) * cnt1f(xx, 10, 14, 6));
        float s1 = pv, s2 = cf * pv;
        #pragma unroll
        for (int d = 32; d; d >>= 1) {
            s1 += __shfl_down(s1, d, 64);
            s2 += __shfl_down(s2, d, 64);
        }
        if ((tid & 63) == 0) { wred[tid >> 6] = s1; wred[4 + (tid >> 6)] = s2; }
        __syncthreads();
        if (tid == 0) {
            int slot = (b & 15) * 256 + (b >> 4);
            ppa[slot] = wred[0] + wred[1] + wred[2] + wred[3];
            pp6[slot] = wred[4] + wred[5] + wred[6] + wred[7];
        }
    } else if (b < 12288) {
        int v = b - 4096;
        int p0 = (v & 127) * 32, c0 = ((v >> 7) & 7) * 32, n = v >> 10;
        int cc = tid >> 3, p4 = (tid & 7) * 4;
        const float* src = x + (((size_t)(n * 256 + c0 + cc)) << 12) + p0 + p4;
        float4 vv = *(const float4*)src;
        // xbar partials (win=6 weighted + unweighted), 8-lane shuffle reduce
        int pg = p0 + p4;
        int y = pg >> 6, xx = pg & 63;
        float cy = (float)cnt1f(y, 10, 14, 6);
        float s6 = cy * ((float)cnt1f(xx, 10, 14, 6) * vv.x
                       + (float)cnt1f(xx + 1, 10, 14, 6) * vv.y
                       + (float)cnt1f(xx + 2, 10, 14, 6) * vv.z
                       + (float)cnt1f(xx + 3, 10, 14, 6) * vv.w);
        float s = vv.x + vv.y + vv.z + vv.w;
        #pragma unroll
        for (int d = 4; d; d >>= 1) {
            s += __shfl_down(s, d, 8);
            s6 += __shfl_down(s6, d, 8);
        }
        if ((tid & 7) == 0) {
            int pblk = v & 127;
            xpa[pblk * 2048 + n * 256 + c0 + cc] = s;
            xp6[pblk * 2048 + n * 256 + c0 + cc] = s6;
        }
        smf[cc * 37 + p4] = vv.x; smf[cc * 37 + p4 + 1] = vv.y;
        smf[cc * 37 + p4 + 2] = vv.z; smf[cc * 37 + p4 + 3] = vv.w;
        __syncthreads();
        int pp = tid >> 3, c4 = (tid & 7) * 4;
        unsigned lo = (unsigned)f2bf(smf[c4 * 37 + pp]) | ((unsigned)f2bf(smf[(c4 + 1) * 37 + pp]) << 16);
        unsigned hi = (unsigned)f2bf(smf[(c4 + 2) * 37 + pp]) | ((unsigned)f2bf(smf[(c4 + 3) * 37 + pp]) << 16);
        *(uint2*)&xbT[(((size_t)(n << 12)) + p0 + pp) * 256 + c0 + c4] = make_uint2(lo, hi);
    } else if (b < 13056) {
        int i = (b - 12288) * 256 + tid;
        wexpb[i] = f2bf(W_exp[i]);
    } else if (b < 13059) {
        int i = b - 13056;
        float* wql = smf;          // 256
        float* red = smf + 256;    // 256
        wql[tid] = wq[tid];
        red[tid] = wq[tid] * b_exp[i * 256 + tid];
        __syncthreads();
        const float* Wb = W_exp + ((size_t)(i * 256)) * 256 + tid;
        float acc = 0.f;
        #pragma unroll 8
        for (int oc = 0; oc < 256; ++oc) acc = fmaf(wql[oc], Wb[(size_t)oc * 256], acc);
        g[i * 256 + tid] = acc;
        for (int s = 128; s > 0; s >>= 1) { if (tid < s) red[tid] += red[tid + s]; __syncthreads(); }
        if (tid == 0) c0out[i] = red[0] + wq_b[0];
    } else if (b < 13827) {
        int v = b - 13059;
        int o = v & 255, jb = v >> 8;
        float* wrow = smf;         // 256
        float* red = smf + 256;    // 256
        wrow[tid] = W_fus[o * 256 + tid];
        __syncthreads();
        int j = jb * 256 + tid;
        float acc = 0.f;
        #pragma unroll 8
        for (int c = 0; c < 256; ++c) acc = fmaf(wrow[c], W_res[(size_t)c * 768 + j], acc);
        Wcat[o * 1024 + 256 + j] = f2bf(acc);
        if (jb == 0) {
            Wcat[o * 1024 + tid] = f2bf(wrow[tid]);
            red[tid] = wrow[tid] * b_res[tid];
            __syncthreads();
            for (int s = 128; s > 0; s >>= 1) { if (tid < s) red[tid] += red[tid + s]; __syncthreads(); }
            if (tid == 0) biasc[o] = red[0] + b_fus[o];
        }
    } else if (b < 13875) {
        int i = (b - 13827) * 256 + tid;   // < 12288 (xq ++ posq)
        zeroreg[i] = 0.f;
    } else if (b < 14643) {                // W_expT[c][r] = W_exp[r][c]  (768x256)
        int idx = (b - 13875) * 256 + tid;
        W_expT[(idx & 255) * 768 + (idx >> 8)] = W_exp[idx];
    } else if (b < 14771) {                // swqT[c][q] (128x256 src)
        int idx = (b - 14643) * 256 + tid;
        swqT[(idx & 255) * 128 + (idx >> 8)] = sp_wq_w[idx];
    } else if (b < 14899) {                // chvT[c][q] (128x256 src)
        int idx = (b - 14771) * 256 + tid;
        chvT[(idx & 255) * 128 + (idx >> 8)] = ch_wv_w[idx];
    } else {                               // chzT[c2][o] (256x128 src)
        int idx = (b - 14899) * 256 + tid;
        chzT[(idx & 127) * 256 + (idx >> 7)] = ch_wz_w[idx];
    }
}

// ---- blocks 0..511: qdot (512 thr, 64 p each; thread owns 4 p via float4,
//      32 c-groups of 8) + softmax partials. blocks 512..535: ubar.
__global__ __launch_bounds__(512) void qdot_ubar(
    const float* __restrict__ x, const float* __restrict__ pos,
    const float* __restrict__ g, const float* __restrict__ c0in,
    const float* __restrict__ wq, float* __restrict__ qdot,
    const float* __restrict__ b_exp,
    const float* __restrict__ xpa, const float* __restrict__ xp6,
    const float* __restrict__ ppa, const float* __restrict__ pp6,
    const float* __restrict__ W_expT, float* __restrict__ ubar,
    float* __restrict__ qpm, float* __restrict__ qpz)
{
    int blk = blockIdx.x, tid = threadIdx.x;
    if (blk < 512) {
        int n = blk >> 6;
        int pq = tid & 15, cg = tid >> 4;          // 16 p-quads x 32 c-groups
        int pb = blk & 63;
        int p = pb * 64 + pq * 4;
        __shared__ float gl[768];
        __shared__ float wql[256];
        __shared__ float4 wp[8][16][4];
        for (int k = tid; k < 768; k += 512) gl[k] = g[k];
        if (tid < 256) wql[tid] = wq[tid];
        __syncthreads();
        const float* xp = x + (((size_t)n) << 20) + p;
        const float* pp = pos + p;
        float4 a0 = make_float4(0.f, 0.f, 0.f, 0.f), a1 = a0, a2 = a0, ap = a0;
        #pragma unroll
        for (int c = cg * 8; c < cg * 8 + 8; ++c) {
            float4 xv = *(const float4*)(xp + ((size_t)c << 12));
            float4 pv = *(const float4*)(pp + ((size_t)c << 12));
            FMA4(a0, gl[c], xv);
            FMA4(a1, gl[256 + c], xv);
            FMA4(a2, gl[512 + c], xv);
            FMA4(ap, wql[c], pv);
        }
        SHRED4(a0); SHRED4(a1); SHRED4(a2); SHRED4(ap);
        int lane = tid & 63, w = tid >> 6;
        if (lane < 16) {
            wp[w][lane][0] = a0; wp[w][lane][1] = a1;
            wp[w][lane][2] = a2; wp[w][lane][3] = ap;
        }
        __syncthreads();
        if (tid < 16) {
            float4 s0 = make_float4(0.f, 0.f, 0.f, 0.f), s1 = s0, s2 = s0, sp = s0;
            #pragma unroll
            for (int w2 = 0; w2 < 8; ++w2) {
                ADD4(s0, wp[w2][tid][0]); ADD4(s1, wp[w2][tid][1]);
                ADD4(s2, wp[w2][tid][2]); ADD4(sp, wp[w2][tid][3]);
            }
            float c00 = c0in[0], c01 = c0in[1], c02 = c0in[2];
            float4 va, vb, vc;
            va.x = s0.x + sp.x + c00; va.y = s0.y + sp.y + c00;
            va.z = s0.z + sp.z + c00; va.w = s0.w + sp.w + c00;
            vb.x = s1.x + sp.x + c01; vb.y = s1.y + sp.y + c01;
            vb.z = s1.z + sp.z + c01; vb.w = s1.w + sp.w + c01;
            vc.x = s2.x + sp.x + c02; vc.y = s2.y + sp.y + c02;
            vc.z = s2.z + sp.z + c02; vc.w = s2.w + sp.w + c02;
            *(float4*)&qdot[((0 * 8 + n) << 12) + p] = va;
            *(float4*)&qdot[((1 * 8 + n) << 12) + p] = vb;
            *(float4*)&qdot[((2 * 8 + n) << 12) + p] = vc;
            int y = p >> 6, xx = p & 63;
            #pragma unroll
            for (int i = 0; i < 3; ++i) {
                int win = 2 * (i + 1), sh = 64 / win, kh = sh + 64 % win;
                float4 v = (i == 0) ? va : (i == 1) ? vb : vc;
                float cy = (float)cnt1f(y, sh, kh, win);
                float cf0 = cy * (float)cnt1f(xx, sh, kh, win);
                float cf1 = cy * (float)cnt1f(xx + 1, sh, kh, win);
                float cf2 = cy * (float)cnt1f(xx + 2, sh, kh, win);
                float cf3 = cy * (float)cnt1f(xx + 3, sh, kh, win);
                float m = fmaxf(fmaxf(v.x, v.y), fmaxf(v.z, v.w));
                #pragma unroll
                for (int d = 8; d; d >>= 1) m = fmaxf(m, __shfl_down(m, d, 16));
                m = __shfl(m, 0, 16);
                float z = cf0 * expf(v.x - m) + cf1 * expf(v.y - m)
                        + cf2 * expf(v.z - m) + cf3 * expf(v.w - m);
                #pragma unroll
                for (int d = 8; d; d >>= 1) z += __shfl_down(z, d, 16);
                if (tid == 0) {
                    int bidx = (i * 8 + n) * 64 + pb;
                    qpm[bidx] = m; qpz[bidx] = z;
                }
            }
        }
    } else {
        int v = blk - 512;
        int i = v >> 3, n = v & 7;
        __shared__ float xbl[256];
        if (tid < 256) {
            const float* xp_ = (i < 2) ? xpa : xp6;
            float s = 0.f;
            #pragma unroll 8
            for (int k = 0; k < 128; ++k) s += xp_[k * 2048 + n * 256 + tid];
            xbl[tid] = s;
        }
        __syncthreads();
        if (tid < 256) {
            const float* pp_ = (i < 2) ? ppa : pp6;
            float pb = 0.f;
            #pragma unroll
            for (int k = 0; k < 16; ++k) pb += pp_[k * 256 + tid];
            int win = 2 * (i + 1), sh = 64 / win, kh = sh + 64 % win;
            float Li = (float)(win * win * kh * kh);
            float acc = b_exp[i * 256 + tid] * Li + pb;
            const float* Wc = W_expT + i * 256 + tid;
            #pragma unroll 8
            for (int j = 0; j < 256; ++j) acc = fmaf(Wc[(size_t)j * 768], xbl[j], acc);
            ubar[(i * 8 + n) * 256 + tid] = acc;
        }
    }
}

// ---- merge softmax partials, spq, w_eff, h, btot (grid 3 x 8, 1024 thr,
//      4-8 way k-split on each matvec — was 24 blocks x 4 waves, latency-bound)
__global__ __launch_bounds__(1024) void pass_b_h(
    const float* __restrict__ ubar_raw,
    const float* __restrict__ swqT, const float* __restrict__ sp_wq_b,
    const float* __restrict__ sp_wv_w, const float* __restrict__ sp_wv_b,
    const float* __restrict__ W_exp, const float* __restrict__ b_exp,
    const float* __restrict__ qpm, const float* __restrict__ qpz,
    float* __restrict__ Mn, float* __restrict__ invZn,
    float* __restrict__ w_eff, float* __restrict__ h, float* __restrict__ btot)
{
    int i = blockIdx.x, n = blockIdx.y, tid = threadIdx.x;
    int b = i * 8 + n;
    int win = 2 * (i + 1), sh = 64 / win, kh = sh + 64 % win;
    float invL = 1.f / (float)(win * win * kh * kh);
    __shared__ float ub[256];
    __shared__ float spq[128];
    __shared__ float we[256];
    __shared__ float ps[1024];
    __shared__ float red[256];
    // merge the 64 per-block (m,z) partials (wave 0 only)
    if (tid < 64) {
        float mp = qpm[b * 64 + tid];
        float zp = qpz[b * 64 + tid];
        float mm = mp;
        #pragma unroll
        for (int d = 32; d; d >>= 1) mm = fmaxf(mm, __shfl_down(mm, d, 64));
        float M = __shfl(mm, 0, 64);
        float zz = zp * expf(mp - M);
        #pragma unroll
        for (int d = 32; d; d >>= 1) zz += __shfl_down(zz, d, 64);
        if (tid == 0) { Mn[b] = M; invZn[b] = 1.f / zz; }
    }
    if (tid < 256) ub[tid] = ubar_raw[b * 256 + tid] * invL;
    __syncthreads();
    // swq matvec: 128 outputs, 8 segs x 32 c
    {
        int q = tid & 127, s8 = tid >> 7;
        float a = 0.f;
        #pragma unroll 8
        for (int c = s8 * 32; c < s8 * 32 + 32; ++c) a = fmaf(swqT[c * 128 + q], ub[c], a);
        ps[tid] = a;
    }
    __syncthreads();
    float sl = 0.f;
    if (tid < 128) {
        float a = sp_wq_b[tid];
        #pragma unroll
        for (int k = 0; k < 8; ++k) a += ps[k * 128 + tid];
        sl = a;
        red[tid] = a;
    }
    __syncthreads();
    for (int s = 64; s > 0; s >>= 1) { if (tid < s) red[tid] = fmaxf(red[tid], red[tid + s]); __syncthreads(); }
    float m2 = red[0]; __syncthreads();
    float e = (tid < 128) ? expf(sl - m2) : 0.f;
    if (tid < 128) red[tid] = e;
    __syncthreads();
    for (int s = 64; s > 0; s >>= 1) { if (tid < s) red[tid] += red[tid + s]; __syncthreads(); }
    float S2 = red[0]; __syncthreads();
    if (tid < 128) spq[tid] = e / S2;
    __syncthreads();
    // weff matvec: 256 outputs, 4 segs x 32 q
    {
        int c = tid & 255, s4 = tid >> 8;
        float a = 0.f;
        #pragma unroll 8
        for (int q = s4 * 32; q < s4 * 32 + 32; ++q) a = fmaf(spq[q], sp_wv_w[q * 256 + c], a);
        ps[tid] = a;
    }
    __syncthreads();
    if (tid < 256) {
        float a = ps[tid] + ps[256 + tid] + ps[512 + tid] + ps[768 + tid];
        w_eff[b * 256 + tid] = a;
        we[tid] = a;
    }
    __syncthreads();
    // h matvec: 256 outputs, 4 segs x 64 oc
    {
        int c = tid & 255, s4 = tid >> 8;
        const float* Wb2 = W_exp + (size_t)i * 65536 + c;
        float a = 0.f;
        #pragma unroll 8
        for (int oc = s4 * 64; oc < s4 * 64 + 64; ++oc) a = fmaf(we[oc], Wb2[(size_t)oc * 256], a);
        ps[tid] = a;
    }
    __syncthreads();
    if (tid < 256) {
        h[b * 256 + tid] = ps[tid] + ps[256 + tid] + ps[512 + tid] + ps[768 + tid];
        red[tid] = we[tid] * b_exp[i * 256 + tid] + ((tid < 128) ? spq[tid] * sp_wv_b[tid] : 0.f);
    }
    __syncthreads();
    for (int s = 128; s > 0; s >>= 1) { if (tid < s) red[tid] += red[tid + s]; __syncthreads(); }
    if (tid == 0) btot[b] = red[0];
}

// --- phase1: spw = sigmoid(h.x + weff.pos + btot), t = cnt*softmax(qdot)
//     (float4 along p; thread owns 4 p, 32 c-groups of 8)
// --- phase2: xq[c]  += sum_p t*xbT[p][c]  (bf16), posq[c] += sum_p t*posT[p][c]
__global__ __launch_bounds__(512) void spw_t_xq(
    const float* __restrict__ x, const float* __restrict__ pos,
    const float* __restrict__ h, const float* __restrict__ weff,
    const float* __restrict__ qdot, const float* __restrict__ Mn,
    const float* __restrict__ invZn, const float* __restrict__ btot,
    const ushort_t* __restrict__ xbT, const float* __restrict__ posT,
    float* __restrict__ spw, float* __restrict__ xq, float* __restrict__ posq)
{
    int n = blockIdx.y, tid = threadIdx.x;
    int pq = tid & 15, cg = tid >> 4;              // 16 p-quads x 32 c-groups
    int p0b = blockIdx.x * 64;
    int p = p0b + pq * 4;
    __shared__ float hl[768], wl[768];
    __shared__ float4 wp[8][16][3];
    __shared__ float tl[3][64];
    for (int k = tid; k < 768; k += 512) {
        int i = k >> 8, c = k & 255;
        hl[k] = h[(i * 8 + n) * 256 + c];
        wl[k] = weff[(i * 8 + n) * 256 + c];
    }
    __syncthreads();
    const float* xp = x + (((size_t)n) << 20) + p;
    const float* pp = pos + p;
    float4 a0 = make_float4(0.f, 0.f, 0.f, 0.f), a1 = a0, a2 = a0;
    #pragma unroll
    for (int c = cg * 8; c < cg * 8 + 8; ++c) {
        float4 xv = *(const float4*)(xp + ((size_t)c << 12));
        float4 pv = *(const float4*)(pp + ((size_t)c << 12));
        FMA4(a0, hl[c], xv);       FMA4(a0, wl[c], pv);
        FMA4(a1, hl[256 + c], xv); FMA4(a1, wl[256 + c], pv);
        FMA4(a2, hl[512 + c], xv); FMA4(a2, wl[512 + c], pv);
    }
    SHRED4(a0); SHRED4(a1); SHRED4(a2);
    int lane = tid & 63, w = tid >> 6;
    if (lane < 16) { wp[w][lane][0] = a0; wp[w][lane][1] = a1; wp[w][lane][2] = a2; }
    __syncthreads();
    if (tid < 16) {
        float4 s0 = make_float4(0.f, 0.f, 0.f, 0.f), s1 = s0, s2 = s0;
        #pragma unroll
        for (int w2 = 0; w2 < 8; ++w2) {
            ADD4(s0, wp[w2][tid][0]); ADD4(s1, wp[w2][tid][1]); ADD4(s2, wp[w2][tid][2]);
        }
        int y = p >> 6, xx = p & 63;
        #pragma unroll
        for (int i = 0; i < 3; ++i) {
            int b = i * 8 + n;
            int win = 2 * (i + 1), sh = 64 / win, kh = sh + 64 % win;
            float4 v = (i == 0) ? s0 : (i == 1) ? s1 : s2;
            float bt = btot[b];
            int idx = (b << 12) + p;
            float4 sv;
            sv.x = 1.f / (1.f + expf(-(v.x + bt)));
            sv.y = 1.f / (1.f + expf(-(v.y + bt)));
            sv.z = 1.f / (1.f + expf(-(v.z + bt)));
            sv.w = 1.f / (1.f + expf(-(v.w + bt)));
            *(float4*)&spw[idx] = sv;
            float cy = (float)cnt1f(y, sh, kh, win);
            float cf0 = cy * (float)cnt1f(xx, sh, kh, win);
            float cf1 = cy * (float)cnt1f(xx + 1, sh, kh, win);
            float cf2 = cy * (float)cnt1f(xx + 2, sh, kh, win);
            float cf3 = cy * (float)cnt1f(xx + 3, sh, kh, win);
            float4 qv = *(const float4*)&qdot[idx];
            float Mb = Mn[b], iZb = invZn[b];
            tl[i][pq * 4 + 0] = cf0 * expf(qv.x - Mb) * iZb;
            tl[i][pq * 4 + 1] = cf1 * expf(qv.y - Mb) * iZb;
            tl[i][pq * 4 + 2] = cf2 * expf(qv.z - Mb) * iZb;
            tl[i][pq * 4 + 3] = cf3 * expf(qv.w - Mb) * iZb;
        }
    }
    __syncthreads();
    // phase 2
    int c = tid & 255;
    int half = tid >> 8;
    float s0 = 0.f, s1 = 0.f, s2 = 0.f;
    if (half == 0) {
        const ushort_t* xb = xbT + (((size_t)((n << 12) + p0b)) << 8) + c;
        #pragma unroll 4
        for (int pl = 0; pl < 64; ++pl) {
            float xv = bf2f(xb[(size_t)pl << 8]);
            s0 = fmaf(tl[0][pl], xv, s0);
            s1 = fmaf(tl[1][pl], xv, s1);
            s2 = fmaf(tl[2][pl], xv, s2);
        }
        atomicAdd(&xq[(0 * 8 + n) * 256 + c], s0);
        atomicAdd(&xq[(1 * 8 + n) * 256 + c], s1);
        atomicAdd(&xq[(2 * 8 + n) * 256 + c], s2);
    } else {
        const float* pt = posT + (((size_t)p0b) << 8) + c;
        #pragma unroll 4
        for (int pl = 0; pl < 64; ++pl) {
            float pv = pt[(size_t)pl << 8];
            s0 = fmaf(tl[0][pl], pv, s0);
            s1 = fmaf(tl[1][pl], pv, s1);
            s2 = fmaf(tl[2][pl], pv, s2);
        }
        atomicAdd(&posq[(0 * 8 + n) * 256 + c], s0);
        atomicAdd(&posq[(1 * 8 + n) * 256 + c], s1);
        atomicAdd(&posq[(2 * 8 + n) * 256 + c], s2);
    }
}

// ---- uq = W_exp_i@xq + b + posq; z->wz->LN->sigmoid->chw (grid 3x8, 1024 thr)
__global__ __launch_bounds__(1024) void pass_d_uq(
    const float* __restrict__ W_expT, const float* __restrict__ b_exp,
    const float* __restrict__ xq, const float* __restrict__ posq,
    const float* __restrict__ chvT, const float* __restrict__ ch_wv_b,
    const float* __restrict__ chzT, const float* __restrict__ ch_wz_b,
    const float* __restrict__ ln_g, const float* __restrict__ ln_b,
    float* __restrict__ ch_w)
{
    int i = blockIdx.x, n = blockIdx.y, tid = threadIdx.x;
    int b = i * 8 + n;
    __shared__ float xql[256];
    __shared__ float uql[256];
    __shared__ float zz[128];
    __shared__ float ps[1024];
    __shared__ float red[256];
    if (tid < 256) xql[tid] = xq[b * 256 + tid];
    __syncthreads();
    // uq matvec: 256 outputs, 4 segs x 64 cin
    {
        int oc = tid & 255, s4 = tid >> 8;
        const float* Wc = W_expT + i * 256 + oc;
        float a = 0.f;
        #pragma unroll 8
        for (int cin = s4 * 64; cin < s4 * 64 + 64; ++cin) a = fmaf(Wc[(size_t)cin * 768], xql[cin], a);
        ps[tid] = a;
    }
    __syncthreads();
    if (tid < 256)
        uql[tid] = b_exp[i * 256 + tid] + posq[b * 256 + tid]
                 + ps[tid] + ps[256 + tid] + ps[512 + tid] + ps[768 + tid];
    __syncthreads();
    // zz matvec: 128 outputs, 8 segs x 32 c
    {
        int q = tid & 127, s8 = tid >> 7;
        float a = 0.f;
        #pragma unroll 8
        for (int c = s8 * 32; c < s8 * 32 + 32; ++c) a = fmaf(chvT[c * 128 + q], uql[c], a);
        ps[tid] = a;
    }
    __syncthreads();
    if (tid < 128) {
        float a = ch_wv_b[tid];
        #pragma unroll
        for (int k = 0; k < 8; ++k) a += ps[k * 128 + tid];
        zz[tid] = a;
    }
    __syncthreads();
    // wz matvec: 256 outputs, 4 segs x 32 c2
    {
        int o = tid & 255, s4 = tid >> 8;
        float a = 0.f;
        #pragma unroll 8
        for (int c2 = s4 * 32; c2 < s4 * 32 + 32; ++c2) a = fmaf(chzT[c2 * 256 + o], zz[c2], a);
        ps[tid] = a;
    }
    __syncthreads();
    float wz = 0.f;
    if (tid < 256) {
        wz = ch_wz_b[tid] + ps[tid] + ps[256 + tid] + ps[512 + tid] + ps[768 + tid];
        red[tid] = wz;
    }
    __syncthreads();
    for (int s = 128; s > 0; s >>= 1) { if (tid < s) red[tid] += red[tid + s]; __syncthreads(); }
    float mean = red[0] * (1.f / 256.f); __syncthreads();
    float d = wz - mean;
    if (tid < 256) red[tid] = d * d;
    __syncthreads();
    for (int s = 128; s > 0; s >>= 1) { if (tid < s) red[tid] += red[tid + s]; __syncthreads(); }
    float var = red[0] * (1.f / 256.f);
    if (tid < 256) {
        float xn = d / sqrtf(var + 1e-5f);
        ch_w[b * 256 + tid] = 1.f / (1.f + expf(-(xn * ln_g[tid] + ln_b[tid])));
    }
}

// ---- MFMA GEMM 1 (LDS-staged gated epilogue): exT bf16 [n][p][768]
//   e = W_exp@x+b;  combined = e + (e + posT)*(chw + spw)
__global__ __launch_bounds__(256) void gemm_expT(
    const ushort_t* __restrict__ Wb, const ushort_t* __restrict__ XT,
    const float* __restrict__ bias, const float* __restrict__ posT,
    const float* __restrict__ chw, const float* __restrict__ spw,
    ushort_t* __restrict__ OutT)
{
    __shared__ ushort_t SM[10240];           // As | Bs ; reused as stage [128][72]
    ushort_t* As = SM;
    ushort_t* Bs = SM + 5120;
    int n = blockIdx.z;
    int p0 = blockIdx.x * 128;
    int o0 = blockIdx.y * 128;
    int t = threadIdx.x;
    int lane = t & 63, wave = t >> 6;
    int wm = (wave & 1) * 64, wn = (wave >> 1) * 64;
    int lr = lane & 15, lk = (lane >> 4) * 8;
    int ar = t >> 2, ac = (t & 3) * 8;
    const ushort_t* A0 = Wb + (size_t)(o0 + ar) * 256 + ac;
    const ushort_t* A1 = Wb + (size_t)(o0 + ar + 64) * 256 + ac;
    const ushort_t* B0 = XT + (((size_t)(n << 12)) + p0 + ar) * 256 + ac;
    const ushort_t* B1 = XT + (((size_t)(n << 12)) + p0 + ar + 64) * 256 + ac;
    floatx4 acc[4][4] = {};
    for (int k0 = 0; k0 < 256; k0 += 32) {
        uint4 a0 = *(const uint4*)(A0 + k0);
        uint4 a1 = *(const uint4*)(A1 + k0);
        uint4 b0 = *(const uint4*)(B0 + k0);
        uint4 b1 = *(const uint4*)(B1 + k0);
        __syncthreads();
        *(uint4*)&As[ar * 40 + ac] = a0;
        *(uint4*)&As[(ar + 64) * 40 + ac] = a1;
        *(uint4*)&Bs[ar * 40 + ac] = b0;
        *(uint4*)&Bs[(ar + 64) * 40 + ac] = b1;
        __syncthreads();
        bf16x8 af[4], bfr[4];
        #pragma unroll
        for (int mi = 0; mi < 4; ++mi)
            af[mi] = *(const bf16x8*)&As[(wm + mi * 16 + lr) * 40 + lk];
        #pragma unroll
        for (int ni = 0; ni < 4; ++ni)
            bfr[ni] = *(const bf16x8*)&Bs[(wn + ni * 16 + lr) * 40 + lk];
        #pragma unroll
        for (int mi = 0; mi < 4; ++mi)
            #pragma unroll
            for (int ni = 0; ni < 4; ++ni)
                acc[mi][ni] = __builtin_amdgcn_mfma_f32_16x16x32_bf16(
                    af[mi], bfr[ni], acc[mi][ni], 0, 0, 0);
    }
    int col = lane & 15, rb = (lane >> 4) * 4;
    int ibr = o0 >> 8;
    int bi = ibr * 8 + n;
    #pragma unroll
    for (int r = 0; r < 2; ++r) {
        __syncthreads();
        if (wm == r * 64) {
            #pragma unroll
            for (int mi = 0; mi < 4; ++mi) {
                int o_loc = mi * 16 + rb;
                float4 bo = *(const float4*)&bias[o0 + r * 64 + o_loc];
                #pragma unroll
                for (int ni = 0; ni < 4; ++ni) {
                    int prow = wn + ni * 16 + col;
                    floatx4 v = acc[mi][ni];
                    unsigned lo = (unsigned)f2bf(v[0] + bo.x) | ((unsigned)f2bf(v[1] + bo.y) << 16);
                    unsigned hi = (unsigned)f2bf(v[2] + bo.z) | ((unsigned)f2bf(v[3] + bo.w) << 16);
                    *(uint2*)&SM[prow * 72 + o_loc] = make_uint2(lo, hi);
                }
            }
        }
        __syncthreads();
        #pragma unroll
        for (int it = 0; it < 4; ++it) {
            int slot = it * 256 + t;
            int pl = slot >> 3, j = (slot & 7) * 8;
            uint4 raw = *(const uint4*)&SM[pl * 72 + j];
            float e0 = bf2f((ushort_t)(raw.x & 0xFFFF)), e1 = bf2f((ushort_t)(raw.x >> 16));
            float e2 = bf2f((ushort_t)(raw.y & 0xFFFF)), e3 = bf2f((ushort_t)(raw.y >> 16));
            float e4 = bf2f((ushort_t)(raw.z & 0xFFFF)), e5 = bf2f((ushort_t)(raw.z >> 16));
            float e6 = bf2f((ushort_t)(raw.w & 0xFFFF)), e7 = bf2f((ushort_t)(raw.w >> 16));
            int p = p0 + pl;
            int cbase = (o0 & 255) + r * 64 + j;
            float s = spw[(bi << 12) + p];
            float4 q0 = *(const float4*)&posT[p * 256 + cbase];
            float4 q1 = *(const float4*)&posT[p * 256 + cbase + 4];
            float4 w0 = *(const float4*)&chw[bi * 256 + cbase];
            float4 w1 = *(const float4*)&chw[bi * 256 + cbase + 4];
            float r0 = e0 + (e0 + q0.x) * (w0.x + s);
            float r1 = e1 + (e1 + q0.y) * (w0.y + s);
            float r2 = e2 + (e2 + q0.z) * (w0.z + s);
            float r3 = e3 + (e3 + q0.w) * (w0.w + s);
            float r4 = e4 + (e4 + q1.x) * (w1.x + s);
            float r5 = e5 + (e5 + q1.y) * (w1.y + s);
            float r6 = e6 + (e6 + q1.z) * (w1.z + s);
            float r7 = e7 + (e7 + q1.w) * (w1.w + s);
            uint4 outv;
            outv.x = (unsigned)f2bf(r0) | ((unsigned)f2bf(r1) << 16);
            outv.y = (unsigned)f2bf(r2) | ((unsigned)f2bf(r3) << 16);
            outv.z = (unsigned)f2bf(r4) | ((unsigned)f2bf(r5) << 16);
            outv.w = (unsigned)f2bf(r6) | ((unsigned)f2bf(r7) << 16);
            *(uint4*)&OutT[(((size_t)(n << 12)) + p) * 768 + o0 + r * 64 + j] = outv;
        }
    }
}

// ---- MFMA GEMM 2: out = Wcat @ [x ; combined] + biasc, fp32 [n][256][4096]
__global__ __launch_bounds__(256) void gemm_out(
    const ushort_t* __restrict__ Wcat, const ushort_t* __restrict__ XT,
    const ushort_t* __restrict__ CT, const float* __restrict__ biasc,
    float* __restrict__ Out)
{
    __shared__ ushort_t As[128 * 40];
    __shared__ ushort_t Bs[128 * 40];
    int n = blockIdx.z;
    int p0 = blockIdx.x * 128;
    int o0 = blockIdx.y * 128;
    int t = threadIdx.x;
    int lane = t & 63, wave = t >> 6;
    int wm = (wave & 1) * 64, wn = (wave >> 1) * 64;
    int lr = lane & 15, lk = (lane >> 4) * 8;
    int ar = t >> 2, ac = (t & 3) * 8;
    const ushort_t* A0 = Wcat + (size_t)(o0 + ar) * 1024 + ac;
    const ushort_t* A1 = Wcat + (size_t)(o0 + ar + 64) * 1024 + ac;
    const ushort_t* BX0 = XT + (((size_t)(n << 12)) + p0 + ar) * 256 + ac;
    const ushort_t* BX1 = XT + (((size_t)(n << 12)) + p0 + ar + 64) * 256 + ac;
    const ushort_t* BC0 = CT + (((size_t)(n << 12)) + p0 + ar) * 768 + ac;
    const ushort_t* BC1 = CT + (((size_t)(n << 12)) + p0 + ar + 64) * 768 + ac;
    floatx4 acc[4][4] = {};
    for (int k0 = 0; k0 < 1024; k0 += 32) {
        const ushort_t* pb0 = (k0 < 256) ? (BX0 + k0) : (BC0 + (k0 - 256));
        const ushort_t* pb1 = (k0 < 256) ? (BX1 + k0) : (BC1 + (k0 - 256));
        uint4 a0 = *(const uint4*)(A0 + k0);
        uint4 a1 = *(const uint4*)(A1 + k0);
        uint4 b0 = *(const uint4*)pb0;
        uint4 b1 = *(const uint4*)pb1;
        __syncthreads();
        *(uint4*)&As[ar * 40 + ac] = a0;
        *(uint4*)&As[(ar + 64) * 40 + ac] = a1;
        *(uint4*)&Bs[ar * 40 + ac] = b0;
        *(uint4*)&Bs[(ar + 64) * 40 + ac] = b1;
        __syncthreads();
        bf16x8 af[4], bfr[4];
        #pragma unroll
        for (int mi = 0; mi < 4; ++mi)
            af[mi] = *(const bf16x8*)&As[(wm + mi * 16 + lr) * 40 + lk];
        #pragma unroll
        for (int ni = 0; ni < 4; ++ni)
            bfr[ni] = *(const bf16x8*)&Bs[(wn + ni * 16 + lr) * 40 + lk];
        #pragma unroll
        for (int mi = 0; mi < 4; ++mi)
            #pragma unroll
            for (int ni = 0; ni < 4; ++ni)
                acc[mi][ni] = __builtin_amdgcn_mfma_f32_16x16x32_bf16(
                    af[mi], bfr[ni], acc[mi][ni], 0, 0, 0);
    }
    int col = lane & 15, rb = (lane >> 4) * 4;
    #pragma unroll
    for (int mi = 0; mi < 4; ++mi) {
        int o = o0 + wm + mi * 16 + rb;
        float4 bo = *(const float4*)&biasc[o];
        #pragma unroll
        for (int r = 0; r < 4; ++r) {
            float br = (r == 0) ? bo.x : (r == 1) ? bo.y : (r == 2) ? bo.z : bo.w;
            #pragma unroll
            for (int ni = 0; ni < 4; ++ni) {
                int p = p0 + wn + ni * 16 + col;
                Out[(((size_t)(n * 256 + o + r)) << 12) + p] = acc[mi][ni][r] + br;
            }
        }
    }
}

// ---------------------------------------------------------------------------
extern "C" void kernel_launch(void* const* d_in, const int* in_sizes, int n_in,
                              void* d_out, int out_size, void* d_ws, size_t ws_size,
                              hipStream_t stream) {
    const float* x        = (const float*)d_in[0];
    const float* w_exp    = (const float*)d_in[1];
    const float* b_exp    = (const float*)d_in[2];
    const float* w_res    = (const float*)d_in[3];
    const float* b_res    = (const float*)d_in[4];
    const float* w_fus    = (const float*)d_in[5];
    const float* b_fus    = (const float*)d_in[6];
    const float* ch_wv_w  = (const float*)d_in[7];
    const float* ch_wv_b  = (const float*)d_in[8];
    const float* ch_wq_w  = (const float*)d_in[9];
    const float* ch_wq_b  = (const float*)d_in[10];
    const float* ch_wz_w  = (const float*)d_in[11];
    const float* ch_wz_b  = (const float*)d_in[12];
    const float* ln_g     = (const float*)d_in[13];
    const float* ln_b     = (const float*)d_in[14];
    const float* sp_wv_w  = (const float*)d_in[15];
    const float* sp_wv_b  = (const float*)d_in[16];
    const float* sp_wq_w  = (const float*)d_in[17];
    const float* sp_wq_b  = (const float*)d_in[18];
    float* out = (float*)d_out;
    float* ws  = (float*)d_ws;

    // workspace layout (float offsets)
    float*    pos   = ws + 0;                      // 1,048,576
    float*    posT  = ws + 1048576;                // 1,048,576
    ushort_t* xbT   = (ushort_t*)(ws + 2097152);   // 8,388,608 ushorts
    ushort_t* exT   = (ushort_t*)(ws + 6291456);   // 25,165,824 ushorts
    ushort_t* wexpb = (ushort_t*)(ws + 18874368);  // 196,608 ushorts
    ushort_t* Wcat  = (ushort_t*)(ws + 18972672);  // 262,144 ushorts
    float*    qdot  = ws + 19103744;   // 98,304
    float*    spw   = ws + 19300352;   // 98,304
    float*    g     = ws + 19398656;   // 768
    float*    c0v   = ws + 19399424;   // 4
    float*    ubar  = ws + 19399428;   // 6,144
    float*    Mn    = ws + 19410180;   // 24
    float*    iZ    = ws + 19410204;   // 24
    float*    weff  = ws + 19410228;   // 6,144
    float*    btot  = ws + 19416372;   // 24
    float*    hb    = ws + 19416396;   // 6,144
    float*    xq    = ws + 19422540;   // 6,144  (zeroed in prep_all)
    float*    posq  = ws + 19428684;   // 6,144  (zeroed in prep_all)
    float*    chw   = ws + 19434828;   // 6,144
    float*    biasc = ws + 19440972;   // 256
    float*    W_expT = ws + 19441228;  // 196,608
    float*    swqT   = ws + 19637836;  // 32,768
    float*    chvT   = ws + 19670604;  // 32,768
    float*    chzT   = ws + 19703372;  // 32,768
    float*    xpa    = ws + 19736140;  // 262,144 (128 pblk x [n*256+c])
    float*    xp6    = ws + 19998284;  // 262,144
    float*    ppa    = ws + 20260428;  // 4,096 (16 slots x 256 c)
    float*    pp6    = ws + 20264524;  // 4,096
    float*    qpm    = ws + 20268620;  // 1,536 (3*8*64 softmax partial max)
    float*    qpz    = ws + 20270156;  // 1,536 (partial expsum)

    prep_all<<<15027, 256, 0, stream>>>(x, w_exp, b_exp, ch_wq_w, ch_wq_b,
                                        w_fus, w_res, b_res, b_fus,
                                        sp_wq_w, ch_wv_w, ch_wz_w,
                                        pos, posT, xbT, wexpb, g, c0v,
                                        Wcat, biasc, xq,
                                        W_expT, swqT, chvT, chzT,
                                        xpa, xp6, ppa, pp6);
    qdot_ubar<<<536, 512, 0, stream>>>(x, pos, g, c0v, ch_wq_w, qdot,
                                       b_exp, xpa, xp6, ppa, pp6, W_expT, ubar,
                                       qpm, qpz);
    pass_b_h<<<dim3(3, 8), 1024, 0, stream>>>(ubar, swqT, sp_wq_b,
                                              sp_wv_w, sp_wv_b, w_exp, b_exp,
                                              qpm, qpz,
                                              Mn, iZ, weff, hb, btot);
    spw_t_xq<<<dim3(64, 8), 512, 0, stream>>>(x, pos, hb, weff, qdot, Mn, iZ,
                                              btot, xbT, posT, spw, xq, posq);
    pass_d_uq<<<dim3(3, 8), 1024, 0, stream>>>(W_expT, b_exp, xq, posq,
                                               chvT, ch_wv_b, chzT, ch_wz_b,
                                               ln_g, ln_b, chw);
    gemm_expT<<<dim3(32, 6, 8), 256, 0, stream>>>(wexpb, xbT, b_exp, posT, chw, spw, exT);
    gemm_out<<<dim3(32, 2, 8), 256, 0, stream>>>(Wcat, xbT, exT, biasc, out);
}